// Round 20
// baseline (548.915 us; speedup 1.0000x reference)
//
// v20 — gemmA: branch-fused (q shared; k2+k3 staged together; 64 MFMA/wave/phase)
#include <hip/hip_runtime.h>
#include <hip/hip_bf16.h>

#define NN 3136
#define CC 512
#define BBATCH 8

typedef unsigned short ush;
typedef unsigned char uch;
typedef __attribute__((ext_vector_type(4))) float f32x4;
typedef __attribute__((ext_vector_type(8))) short short8;

static __device__ __forceinline__ unsigned int pkbf(float a, float b) {
    union { __hip_bfloat162 h; unsigned int u; } v;
    v.h = __float22bfloat162_rn(make_float2(a, b));
    return v.u;
}
static __device__ __forceinline__ ush sbf(float a) {
    union { __hip_bfloat16 h; ush u; } v;
    v.h = __float2bfloat16(a);
    return v.u;
}
static __device__ __forceinline__ unsigned int pk4fp8(float a, float b, float c, float d) {
    unsigned int r = 0;
    r = __builtin_amdgcn_cvt_pk_fp8_f32(a, b, r, false);
    r = __builtin_amdgcn_cvt_pk_fp8_f32(c, d, r, true);
    return r;
}
static __device__ __forceinline__ void gl_lds16(const void* g, void* l) {
    __builtin_amdgcn_global_load_lds((const __attribute__((address_space(1))) void*)g,
                                     (__attribute__((address_space(3))) void*)l, 16, 0, 0);
}

// ---- ws layout (bytes) ----
static constexpr size_t TEN_ELE  = (size_t)BBATCH * NN * CC;   // fp8 bytes
static constexpr size_t VROW     = 3200;
static constexpr size_t VTEN     = (size_t)BBATCH * CC * VROW;
static constexpr size_t INV_OFS  = 0;
static constexpr size_t DEN_OFS  = 301056;
static constexpr size_t PREP_OFS = 501760;
static constexpr size_t VBF_OFS  = PREP_OFS + 3 * TEN_ELE;
static constexpr size_t P_OFS    = VBF_OFS + 2 * VTEN;
static constexpr size_t PER_TILE = 2ull * BBATCH * 128 * VROW;

// ---------------- prepT (unchanged) ----------------
__global__ void prepT_k(const float* __restrict__ f1, const float* __restrict__ f2,
                        const float* __restrict__ f3, float* __restrict__ ssq,
                        uch* __restrict__ prep, uch* __restrict__ vbf) {
    __shared__ float lt[64][65];
    const int tid = threadIdx.x;
    const int xt = blockIdx.x, yc = blockIdx.y, z = blockIdx.z;
    const int t = z >> 3, b = z & 7;
    const float* f = (t == 0) ? f1 : (t == 1) ? f2 : f3;
    const int n0 = xt * 64, c0 = yc * 64;
    const float* src = f + (size_t)b * CC * NN + (size_t)c0 * NN + n0;
    {
        const int col4 = (tid & 15) * 4, rw = tid >> 4;
#pragma unroll
        for (int p = 0; p < 4; ++p) {
            int row = p * 16 + rw;
            f32x4 v = *(const f32x4*)&src[(size_t)row * NN + col4];
            lt[row][col4 + 0] = v[0]; lt[row][col4 + 1] = v[1];
            lt[row][col4 + 2] = v[2]; lt[row][col4 + 3] = v[3];
        }
    }
    __syncthreads();
    {
        uch* dst = prep + (size_t)t * TEN_ELE + ((size_t)b * NN + n0) * CC + c0;
        float* sq = ssq + (size_t)t * BBATCH * NN + (size_t)b * NN + n0;
        const int cchunk = tid & 7, nr = tid >> 3;
#pragma unroll
        for (int p = 0; p < 2; ++p) {
            int n = p * 32 + nr;
            float x0 = lt[cchunk * 8 + 0][n], x1 = lt[cchunk * 8 + 1][n];
            float x2 = lt[cchunk * 8 + 2][n], x3 = lt[cchunk * 8 + 3][n];
            float x4 = lt[cchunk * 8 + 4][n], x5 = lt[cchunk * 8 + 5][n];
            float x6 = lt[cchunk * 8 + 6][n], x7 = lt[cchunk * 8 + 7][n];
            uint2 y = { pk4fp8(x0, x1, x2, x3), pk4fp8(x4, x5, x6, x7) };
            *(uint2*)&dst[(size_t)n * CC + cchunk * 8] = y;
            float s = x0*x0 + x1*x1 + x2*x2 + x3*x3 + x4*x4 + x5*x5 + x6*x6 + x7*x7;
            s += __shfl_xor(s, 1); s += __shfl_xor(s, 2); s += __shfl_xor(s, 4);
            if (cchunk == 0) atomicAdd(&sq[n], s);
        }
    }
    if (t > 0) {
        uch* vout = vbf + (size_t)(t - 1) * VTEN + ((size_t)b * CC + c0) * VROW;
        const int cr = tid >> 2, nq = (tid & 3) * 16;
        float* row = lt[cr];
        uint4 y = { pk4fp8(row[nq+0], row[nq+1], row[nq+2], row[nq+3]),
                    pk4fp8(row[nq+4], row[nq+5], row[nq+6], row[nq+7]),
                    pk4fp8(row[nq+8], row[nq+9], row[nq+10], row[nq+11]),
                    pk4fp8(row[nq+12], row[nq+13], row[nq+14], row[nq+15]) };
        *(uint4*)&vout[(size_t)cr * VROW + n0 + nq] = y;
        if (xt == 48) {
            uint4 z4 = {0u, 0u, 0u, 0u};
            *(uint4*)&vout[(size_t)cr * VROW + 3136 + (tid & 3) * 16] = z4;
        }
    }
}

// ---------------- ssq -> inv ----------------
__global__ void rsqrt_k(float* __restrict__ v) {
    int g = blockIdx.x * 256 + threadIdx.x;
    if (g < 3 * BBATCH * NN) v[g] = 1.0f / fmaxf(sqrtf(v[g]), 1e-12f);
}

// ---------------- gemmA: branch-fused, BK=64 dbuf; epilogue x2; P + den ----------------
__global__ __launch_bounds__(256) void gemmA_k(const uch* __restrict__ prep,
        const float* __restrict__ inv, uch* __restrict__ P, size_t PBRel,
        float* __restrict__ den, int cbt, int rowcap) {
    __shared__ __align__(16) uch sm[49152];       // dbuf 2x{q 8K|k2 8K|k3 8K}; PT aliases
    ush* PT = (ush*)sm;
    const int tid = threadIdx.x, w = tid >> 6, l = tid & 63;
    const int mt = blockIdx.x % 25, ntl = blockIdx.x / 25;
    const int b = blockIdx.y;
    const int n0 = (cbt + ntl) * 128, m0 = mt * 128;
    const uch* qT = prep + (size_t)b * NN * CC;
    const uch* kT2 = prep + TEN_ELE + (size_t)b * NN * CC;
    const uch* kT3 = prep + 2 * TEN_ELE + (size_t)b * NN * CC;
    const int srow = l >> 2, c4p = l & 3;
    const int g = l >> 4, li = l & 15, nh = w & 1, mh = w >> 1;
    f32x4 acc2[4][4], acc3[4][4];
#pragma unroll
    for (int i = 0; i < 4; ++i)
#pragma unroll
        for (int j = 0; j < 4; ++j) {
            acc2[i][j] = (f32x4){0.f, 0.f, 0.f, 0.f};
            acc3[i][j] = (f32x4){0.f, 0.f, 0.f, 0.f};
        }

    auto stageA = [&](int kk, int bb) {
        int c0k = kk * 64;
        uch* dst = sm + bb * 24576;
#pragma unroll
        for (int i = 0; i < 2; ++i) {
            int rowT = i * 64 + w * 16 + srow;    // 0..127
            int rA = n0 + rowT; rA = rA < NN ? rA : NN - 1;
            int rB = m0 + rowT; rB = rB < NN ? rB : NN - 1;
            int co = (c4p ^ ((rowT >> 1) & 3)) << 4;
            gl_lds16(qT  + (size_t)rA * CC + c0k + co, dst + i * 4096 + w * 1024);
            gl_lds16(kT2 + (size_t)rB * CC + c0k + co, dst + 8192 + i * 4096 + w * 1024);
            gl_lds16(kT3 + (size_t)rB * CC + c0k + co, dst + 16384 + i * 4096 + w * 1024);
        }
    };

    stageA(0, 0);
    __syncthreads();

    for (int kk = 0; kk < 8; ++kk) {
        int cur = kk & 1;
        if (kk < 7) stageA(kk + 1, cur ^ 1);
        const uch* smc = sm + cur * 24576;
#pragma unroll
        for (int ks = 0; ks < 2; ++ks) {
            long af[4], b2f[4], b3f[4];
            int kc = ks * 2 + (g >> 1);
#pragma unroll
            for (int i = 0; i < 4; ++i) {
                int rA = nh * 64 + i * 16 + li;
                int oA = ((kc ^ ((rA >> 1) & 3)) << 4) | ((g & 1) << 3);
                af[i] = *(const long*)(smc + rA * 64 + oA);
                int rB = mh * 64 + i * 16 + li;
                int oB = ((kc ^ ((rB >> 1) & 3)) << 4) | ((g & 1) << 3);
                b2f[i] = *(const long*)(smc + 8192 + rB * 64 + oB);
                b3f[i] = *(const long*)(smc + 16384 + rB * 64 + oB);
            }
#pragma unroll
            for (int i = 0; i < 4; ++i)
#pragma unroll
                for (int j = 0; j < 4; ++j) {
                    acc2[i][j] = __builtin_amdgcn_mfma_f32_16x16x32_fp8_fp8(af[i], b2f[j], acc2[i][j], 0, 0, 0);
                    acc3[i][j] = __builtin_amdgcn_mfma_f32_16x16x32_fp8_fp8(af[i], b3f[j], acc3[i][j], 0, 0, 0);
                }
        }
        __syncthreads();
    }
    // shared i1v (minus folded); per-branch epilogue, statically instantiated
    const float* i1p = inv + (size_t)b * NN;
    float i1v[4][4];
#pragma unroll
    for (int i = 0; i < 4; ++i)
#pragma unroll
        for (int r = 0; r < 4; ++r) {
            int n = n0 + nh * 64 + i * 16 + 4 * g + r;
            i1v[i][r] = -i1p[n < NN ? n : NN - 1];
        }
    const int rowlim = (NN - n0) < 128 ? (NN - n0) : 128;
    const int mchunks = (NN - m0) < 128 ? ((NN - m0) >> 3) : 16;
    const int ck = tid & 15, rbase = tid >> 4;

    auto epi = [&](f32x4 (&A)[4][4], int brc) {
        const float* ikp = inv + (size_t)(1 + brc) * (BBATCH * NN) + (size_t)b * NN;
        float ikv[4];
#pragma unroll
        for (int j = 0; j < 4; ++j) {
            int m = m0 + mh * 64 + j * 16 + li;
            ikv[j] = ikp[m < NN ? m : NN - 1];
        }
        __syncthreads();                           // PT free (prev pass reads done)
#pragma unroll
        for (int i = 0; i < 4; ++i)
#pragma unroll
            for (int j = 0; j < 4; ++j) {
                int col = mh * 64 + j * 16 + li;
#pragma unroll
                for (int r = 0; r < 4; ++r) {
                    int row = nh * 64 + i * 16 + 4 * g + r;
                    PT[row * 136 + col] = sbf(__expf(A[i][j][r] * i1v[i][r] * ikv[j]));
                }
            }
        __syncthreads();
        uch* Pg = P + (size_t)brc * PBRel + ((size_t)b * rowcap + (size_t)ntl * 128) * VROW;
        float* denp = den + (size_t)(brc * BBATCH + b) * NN;
#pragma unroll
        for (int pass = 0; pass < 8; ++pass) {
            int rr = rbase + pass * 16;
            uint4 v = *(const uint4*)&PT[rr * 136 + ck * 8];
            unsigned vv[4] = { v.x, v.y, v.z, v.w };
            float fv[8];
#pragma unroll
            for (int q = 0; q < 4; ++q) {
                union { unsigned u; float f; } lo, hi;
                lo.u = vv[q] << 16; hi.u = vv[q] & 0xffff0000u;
                fv[2 * q] = lo.f; fv[2 * q + 1] = hi.f;
            }
            float s = 0.f;
            if (ck < mchunks)
                s = ((fv[0] + fv[1]) + (fv[2] + fv[3])) + ((fv[4] + fv[5]) + (fv[6] + fv[7]));
            s += __shfl_xor(s, 1); s += __shfl_xor(s, 2);
            s += __shfl_xor(s, 4); s += __shfl_xor(s, 8);
            if (ck == 0 && rr < rowlim) atomicAdd(&denp[n0 + rr], s);
            if (rr < rowlim) {
                uint2 pv = {0u, 0u};
                if (ck < mchunks) {
                    pv.x = pk4fp8(fv[0], fv[1], fv[2], fv[3]);
                    pv.y = pk4fp8(fv[4], fv[5], fv[6], fv[7]);
                }
                *(uint2*)&Pg[(size_t)rr * VROW + m0 + ck * 8] = pv;
            }
        }
    };
    epi(acc2, 0);
    epi(acc3, 1);
}

// ---------------- gemmB: 128² tile + 2-phase dbuf pipeline (proven v17) ----------------
__global__ __launch_bounds__(256) void gemmB_k(const uch* __restrict__ vbf,
        const uch* __restrict__ P, size_t PBRel, const float* __restrict__ den,
        const float* __restrict__ fm1, float* __restrict__ out, int cbt, int rowcap) {
    __shared__ __align__(16) uch sm[65536];       // 2 x { V 16KB | P 16KB }
    const int tid = threadIdx.x, w = tid >> 6, l = tid & 63;
    const int ct = blockIdx.x & 3, ntl = blockIdx.x >> 2;
    const int b = blockIdx.y;
    const int c0 = ct * 128, n0 = (cbt + ntl) * 128;
    const int lr8 = l >> 3, c4p = l & 7;
    const int g = l >> 4, li = l & 15, ch = w & 1, nh = w >> 1;
    const float* d2p = den + (size_t)b * NN;
    const float* d3p = den + (size_t)(BBATCH + b) * NN;
    float d2[4], d3[4];
#pragma unroll
    for (int j = 0; j < 4; ++j) {
        int n = n0 + nh * 64 + j * 16 + li;
        int nc = n < NN ? n : NN - 1;
        d2[j] = d2p[nc]; d3[j] = d3p[nc];
    }
    f32x4 acc[4][4];
#pragma unroll
    for (int i = 0; i < 4; ++i)
#pragma unroll
        for (int j = 0; j < 4; ++j) acc[i][j] = (f32x4){0.f, 0.f, 0.f, 0.f};
    const int rowclamp = (NN - 1 - n0) < 127 ? (NN - 1 - n0) : 127;

    auto stage = [&](int gk, int bb) {
        int brr = gk < 25 ? 1 : 0;                 // P3 first, ratio-fold, then P2
        int km = gk < 25 ? gk : gk - 25;
        const uch* vA = vbf + (size_t)brr * VTEN + (size_t)b * CC * VROW;
        const uch* pB = P + (size_t)brr * PBRel + ((size_t)b * rowcap + (size_t)ntl * 128) * VROW;
        int mm0 = km * 128;
        uch* dst = sm + bb * 32768;
#pragma unroll
        for (int i = 0; i < 4; ++i) {
            int rowT = i * 32 + w * 8 + lr8;
            int co = (c4p ^ (rowT & 7)) << 4;
            int rloc = rowT < rowclamp ? rowT : rowclamp;
            gl_lds16(vA + (size_t)(c0 + rowT) * VROW + mm0 + co, dst + i * 4096 + w * 1024);
            gl_lds16(pB + (size_t)rloc * VROW + mm0 + co, dst + 16384 + i * 4096 + w * 1024);
        }
    };

    stage(0, 0);
    __syncthreads();

    for (int gk = 0; gk < 50; ++gk) {
        int cur = gk & 1;
        if (gk < 49) stage(gk + 1, cur ^ 1);
        const uch* smc = sm + cur * 32768;
#pragma unroll
        for (int ks = 0; ks < 4; ++ks) {
            long af[4], bf[4];
#pragma unroll
            for (int i = 0; i < 4; ++i) {
                int rA = ch * 64 + i * 16 + li;
                af[i] = *(const long*)(smc + rA * 128 +
                        ((((2 * ks + (g >> 1)) ^ (rA & 7)) << 4) | ((g & 1) << 3)));
                int rB = nh * 64 + i * 16 + li;
                bf[i] = *(const long*)(smc + 16384 + rB * 128 +
                        ((((2 * ks + (g >> 1)) ^ (rB & 7)) << 4) | ((g & 1) << 3)));
            }
#pragma unroll
            for (int i = 0; i < 4; ++i)
#pragma unroll
                for (int j = 0; j < 4; ++j)
                    acc[i][j] = __builtin_amdgcn_mfma_f32_16x16x32_fp8_fp8(af[i], bf[j], acc[i][j], 0, 0, 0);
        }
        if (gk == 24) {
#pragma unroll
            for (int j = 0; j < 4; ++j) {
                float ratio = d2[j] / fmaxf(d3[j], 1e-30f);
#pragma unroll
                for (int i = 0; i < 4; ++i)
#pragma unroll
                    for (int r = 0; r < 4; ++r) acc[i][j][r] *= ratio;
            }
        }
        __syncthreads();
    }
    const float* fb = fm1 + (size_t)b * CC * NN;
    float* ob = out + (size_t)b * CC * NN;
#pragma unroll
    for (int j = 0; j < 4; ++j) {
        int n = n0 + nh * 64 + j * 16 + li;
        if (n < NN) {
            float s2 = 0.001f / fmaxf(d2[j], 1e-30f);
#pragma unroll
            for (int i = 0; i < 4; ++i) {
                int cc = c0 + ch * 64 + i * 16 + 4 * g;
#pragma unroll
                for (int r = 0; r < 4; ++r) {
                    size_t o = (size_t)(cc + r) * NN + n;
                    ob[o] = fb[o] + s2 * acc[i][j][r];
                }
            }
        }
    }
}

// ================= fallback (proven R5 fused kernel, used only if ws too small) ===============
__global__ void norms_k(const float* __restrict__ f1, const float* __restrict__ f2,
                        const float* __restrict__ f3, float* __restrict__ inv) {
    int gg = blockIdx.x * 256 + threadIdx.x;
    int t = gg / (BBATCH * NN);
    int r = gg - t * (BBATCH * NN);
    int b = r / NN;
    int n = r - b * NN;
    const float* f = (t == 0) ? f1 : (t == 1) ? f2 : f3;
    const float* p = f + (size_t)b * CC * NN + n;
    float ss = 0.f;
#pragma unroll 8
    for (int c = 0; c < CC; ++c) { float x = p[(size_t)c * NN]; ss = fmaf(x, x, ss); }
    inv[gg] = 1.0f / fmaxf(sqrtf(ss), 1e-12f);
}
__global__ void init_k(const float4* __restrict__ src, float4* __restrict__ dst) {
    int gg = blockIdx.x * 256 + threadIdx.x;
    dst[gg] = src[gg];
}
static constexpr int FKTOFF = 16384, FVBASE = 32768, FVOFF = 20480, FPBASE = 73728, FVSTR = 40;
__launch_bounds__(512, 2)
__global__ void attn_fb_k(const float* __restrict__ fq_all, const float* __restrict__ f2_all,
                          const float* __restrict__ f3_all, const float* __restrict__ invws,
                          float* __restrict__ out) {
    __shared__ __align__(16) ush smem[2 * 16384 + 2 * 20480 + 64 * 40];
    __shared__ float denbuf[8][16];
    ush* pp = smem + FPBASE;
    ush* qstage = smem;
    const int tid = threadIdx.x, w = tid >> 6, l = tid & 63;
    const int u = blockIdx.x, batch = u & 7, unit = u >> 3, br = unit & 1, qt = unit >> 1;
    const int n0 = qt * 64;
    const float* fq = fq_all + (size_t)batch * CC * NN;
    const float* fk = (br ? f3_all : f2_all) + (size_t)batch * CC * NN;
    const float* inv1 = invws + batch * NN;
    const float* invk = invws + (1 + br) * (BBATCH * NN) + batch * NN;
    {
        int n = tid & 63, grp = tid >> 6;
        float s = -inv1[n0 + n];
        const float* src = fq + n0 + n;
        int sw = (n & 7) << 3;
#pragma unroll 4
        for (int ssi = 0; ssi < 16; ++ssi) {
            int cb = grp * 4 + 32 * ssi; int b0 = cb * NN;
            uint2 y = { pkbf(src[b0] * s, src[b0 + NN] * s),
                        pkbf(src[b0 + 2 * NN] * s, src[b0 + 3 * NN] * s) };
            *(uint2*)&qstage[n * 512 + (cb ^ sw)] = y;
        }
    }
    __syncthreads();
    short8 qf[16];
    {
        int nQ = 16 * (w & 3) + (l & 15);
        int sw = (nQ & 7) << 3;
#pragma unroll
        for (int ks = 0; ks < 16; ++ks)
            qf[ks] = *(const short8*)&qstage[nQ * 512 + ((ks * 32 + ((l >> 4) << 3)) ^ sw)];
    }
    __syncthreads();
    auto stage = [&](int it, int bb2) {
        int m = tid & 31, grp = tid >> 5;
        int m0 = it * 32;
        float sk = invk[m0 + m];
        const float* src = fk + m0 + m;
        ush* KT = smem + (bb2 ? FKTOFF : 0);
        ush* V = smem + FVBASE + (bb2 ? FVOFF : 0);
        int swm = (m & 7) << 3;
        float xb[32];
#pragma unroll
        for (int ssi = 0; ssi < 8; ++ssi) {
            int b0 = (grp * 4 + 64 * ssi) * NN;
            xb[ssi * 4 + 0] = src[b0]; xb[ssi * 4 + 1] = src[b0 + NN];
            xb[ssi * 4 + 2] = src[b0 + 2 * NN]; xb[ssi * 4 + 3] = src[b0 + 3 * NN];
        }
#pragma unroll
        for (int ssi = 0; ssi < 8; ++ssi) {
            int cb = grp * 4 + 64 * ssi;
            uint2 y = { pkbf(xb[ssi * 4 + 0] * sk, xb[ssi * 4 + 1] * sk),
                        pkbf(xb[ssi * 4 + 2] * sk, xb[ssi * 4 + 3] * sk) };
            *(uint2*)&KT[m * 512 + (cb ^ swm)] = y;
            ush* vb = &V[cb * FVSTR + m];
            vb[0] = sbf(xb[ssi * 4 + 0]); vb[FVSTR] = sbf(xb[ssi * 4 + 1]);
            vb[2 * FVSTR] = sbf(xb[ssi * 4 + 2]); vb[3 * FVSTR] = sbf(xb[ssi * 4 + 3]);
        }
    };
    f32x4 acc[8][2];
#pragma unroll
    for (int ci = 0; ci < 8; ++ci) { acc[ci][0] = (f32x4){0,0,0,0}; acc[ci][1] = (f32x4){0,0,0,0}; }
    float den_part = 0.f;
    stage(0, 0);
    const int mt = w >> 2, nt = w & 3, np = w & 1, cg = w >> 1;
    const int g = l >> 4, li = l & 15;
    const int mA = 16 * mt + li, swA = (mA & 7) << 3, nP = 16 * nt + li;
    for (int it = 0; it < 98; ++it) {
        int bb2 = it & 1;
        __syncthreads();
        f32x4 sacc = (f32x4){0,0,0,0};
        const ush* KT = smem + (bb2 ? FKTOFF : 0);
#pragma unroll
        for (int ks = 0; ks < 16; ++ks) {
            short8 af = *(const short8*)&KT[mA * 512 + ((ks * 32 + (g << 3)) ^ swA)];
            sacc = __builtin_amdgcn_mfma_f32_16x16x32_bf16(af, qf[ks], sacc, 0, 0, 0);
        }
        float p0 = __expf(sacc[0]), p1 = __expf(sacc[1]);
        float p2 = __expf(sacc[2]), p3 = __expf(sacc[3]);
        den_part += (p0 + p1) + (p2 + p3);
        uint2 pw = { pkbf(p0, p1), pkbf(p2, p3) };
        *(uint2*)&pp[nP * FVSTR + 16 * mt + 4 * g] = pw;
        if (it != 97) stage(it + 1, bb2 ^ 1);
        __syncthreads();
        const ush* V = smem + FVBASE + (bb2 ? FVOFF : 0);
        short8 bf0 = *(const short8*)&pp[(32 * np + li) * FVSTR + (g << 3)];
        short8 bf1 = *(const short8*)&pp[(32 * np + 16 + li) * FVSTR + (g << 3)];
        const ush* vbase = &V[(128 * cg + li) * FVSTR + (g << 3)];
#pragma unroll
        for (int ci = 0; ci < 8; ++ci) {
            short8 af = *(const short8*)&vbase[ci * 16 * FVSTR];
            acc[ci][0] = __builtin_amdgcn_mfma_f32_16x16x32_bf16(af, bf0, acc[ci][0], 0, 0, 0);
            acc[ci][1] = __builtin_amdgcn_mfma_f32_16x16x32_bf16(af, bf1, acc[ci][1], 0, 0, 0);
        }
    }
    den_part += __shfl_xor(den_part, 16);
    den_part += __shfl_xor(den_part, 32);
    if (l < 16) denbuf[w][l] = den_part;
    __syncthreads();
    float sc0 = 0.001f / (denbuf[2 * np + 0][li] + denbuf[4 + 2 * np + 0][li]);
    float sc1 = 0.001f / (denbuf[2 * np + 1][li] + denbuf[4 + 2 * np + 1][li]);
    float* op = out + (size_t)batch * CC * NN + n0;
    const int nc0 = 16 * (2 * np + 0) + li, nc1 = 16 * (2 * np + 1) + li;
#pragma unroll
    for (int ci = 0; ci < 8; ++ci) {
        int cbase = 16 * (8 * cg + ci) + 4 * g;
#pragma unroll
        for (int r = 0; r < 4; ++r) {
            atomicAdd(&op[(size_t)(cbase + r) * NN + nc0], acc[ci][0][r] * sc0);
            atomicAdd(&op[(size_t)(cbase + r) * NN + nc1], acc[ci][1][r] * sc1);
        }
    }
}

extern "C" void kernel_launch(void* const* d_in, const int* in_sizes, int n_in,
                              void* d_out, int out_size, void* d_ws, size_t ws_size,
                              hipStream_t stream) {
    (void)in_sizes; (void)n_in; (void)out_size;
    const float* f1 = (const float*)d_in[0];
    const float* f2 = (const float*)d_in[1];
    const float* f3 = (const float*)d_in[2];
    float* out = (float*)d_out;
    char* ws = (char*)d_ws;

    if (ws_size >= P_OFS + PER_TILE) {
        size_t tmax = (ws_size - P_OFS) / PER_TILE;
        int T = tmax < 25 ? (int)tmax : 25;
        int rowcap = T * 128;
        size_t PBRel = (size_t)BBATCH * rowcap * VROW;   // bytes per branch
        float* ssq = (float*)(ws + INV_OFS);
        float* den = (float*)(ws + DEN_OFS);
        uch* prep = (uch*)(ws + PREP_OFS);
        uch* vbf = (uch*)(ws + VBF_OFS);
        uch* P = (uch*)(ws + P_OFS);
        hipMemsetAsync(ws, 0, DEN_OFS + 200704, stream);
        prepT_k<<<dim3(49, 8, 24), 256, 0, stream>>>(f1, f2, f3, ssq, prep, vbf);
        rsqrt_k<<<294, 256, 0, stream>>>(ssq);
        for (int cbt = 0; cbt < 25; ) {
            int t = (25 - cbt) < T ? (25 - cbt) : T;
            gemmA_k<<<dim3(25 * t, 8), 256, 0, stream>>>(prep, ssq, P, PBRel, den, cbt, rowcap);
            gemmB_k<<<dim3(4 * t, 8), 256, 0, stream>>>(vbf, P, PBRel, den, f1, out, cbt, rowcap);
            cbt += t;
        }
    } else {
        float* inv = (float*)(ws + INV_OFS);
        norms_k<<<294, 256, 0, stream>>>(f1, f2, f3, inv);
        init_k<<<12544, 256, 0, stream>>>((const float4*)f1, (float4*)out);
        attn_fb_k<<<784, 512, 0, stream>>>(f1, f2, f3, inv, out);
    }
}

// Round 21
// 497.126 us; speedup vs baseline: 1.1042x; 1.1042x over previous
//
// v21 — gemmA = v19 loop + lean epilogue (exp2-fold, fp8 PT pure-copy bounce, den-from-regs)
#include <hip/hip_runtime.h>
#include <hip/hip_bf16.h>

#define NN 3136
#define CC 512
#define BBATCH 8

typedef unsigned short ush;
typedef unsigned char uch;
typedef __attribute__((ext_vector_type(4))) float f32x4;
typedef __attribute__((ext_vector_type(8))) short short8;

static __device__ __forceinline__ unsigned int pkbf(float a, float b) {
    union { __hip_bfloat162 h; unsigned int u; } v;
    v.h = __float22bfloat162_rn(make_float2(a, b));
    return v.u;
}
static __device__ __forceinline__ ush sbf(float a) {
    union { __hip_bfloat16 h; ush u; } v;
    v.h = __float2bfloat16(a);
    return v.u;
}
static __device__ __forceinline__ unsigned int pk4fp8(float a, float b, float c, float d) {
    unsigned int r = 0;
    r = __builtin_amdgcn_cvt_pk_fp8_f32(a, b, r, false);
    r = __builtin_amdgcn_cvt_pk_fp8_f32(c, d, r, true);
    return r;
}
static __device__ __forceinline__ void gl_lds16(const void* g, void* l) {
    __builtin_amdgcn_global_load_lds((const __attribute__((address_space(1))) void*)g,
                                     (__attribute__((address_space(3))) void*)l, 16, 0, 0);
}

// ---- ws layout (bytes) ----
static constexpr size_t TEN_ELE  = (size_t)BBATCH * NN * CC;   // fp8 bytes
static constexpr size_t VROW     = 3200;
static constexpr size_t VTEN     = (size_t)BBATCH * CC * VROW;
static constexpr size_t INV_OFS  = 0;
static constexpr size_t DEN_OFS  = 301056;
static constexpr size_t PREP_OFS = 501760;
static constexpr size_t VBF_OFS  = PREP_OFS + 3 * TEN_ELE;
static constexpr size_t P_OFS    = VBF_OFS + 2 * VTEN;
static constexpr size_t PER_TILE = 2ull * BBATCH * 128 * VROW;

// ---------------- prepT (unchanged) ----------------
__global__ void prepT_k(const float* __restrict__ f1, const float* __restrict__ f2,
                        const float* __restrict__ f3, float* __restrict__ ssq,
                        uch* __restrict__ prep, uch* __restrict__ vbf) {
    __shared__ float lt[64][65];
    const int tid = threadIdx.x;
    const int xt = blockIdx.x, yc = blockIdx.y, z = blockIdx.z;
    const int t = z >> 3, b = z & 7;
    const float* f = (t == 0) ? f1 : (t == 1) ? f2 : f3;
    const int n0 = xt * 64, c0 = yc * 64;
    const float* src = f + (size_t)b * CC * NN + (size_t)c0 * NN + n0;
    {
        const int col4 = (tid & 15) * 4, rw = tid >> 4;
#pragma unroll
        for (int p = 0; p < 4; ++p) {
            int row = p * 16 + rw;
            f32x4 v = *(const f32x4*)&src[(size_t)row * NN + col4];
            lt[row][col4 + 0] = v[0]; lt[row][col4 + 1] = v[1];
            lt[row][col4 + 2] = v[2]; lt[row][col4 + 3] = v[3];
        }
    }
    __syncthreads();
    {
        uch* dst = prep + (size_t)t * TEN_ELE + ((size_t)b * NN + n0) * CC + c0;
        float* sq = ssq + (size_t)t * BBATCH * NN + (size_t)b * NN + n0;
        const int cchunk = tid & 7, nr = tid >> 3;
#pragma unroll
        for (int p = 0; p < 2; ++p) {
            int n = p * 32 + nr;
            float x0 = lt[cchunk * 8 + 0][n], x1 = lt[cchunk * 8 + 1][n];
            float x2 = lt[cchunk * 8 + 2][n], x3 = lt[cchunk * 8 + 3][n];
            float x4 = lt[cchunk * 8 + 4][n], x5 = lt[cchunk * 8 + 5][n];
            float x6 = lt[cchunk * 8 + 6][n], x7 = lt[cchunk * 8 + 7][n];
            uint2 y = { pk4fp8(x0, x1, x2, x3), pk4fp8(x4, x5, x6, x7) };
            *(uint2*)&dst[(size_t)n * CC + cchunk * 8] = y;
            float s = x0*x0 + x1*x1 + x2*x2 + x3*x3 + x4*x4 + x5*x5 + x6*x6 + x7*x7;
            s += __shfl_xor(s, 1); s += __shfl_xor(s, 2); s += __shfl_xor(s, 4);
            if (cchunk == 0) atomicAdd(&sq[n], s);
        }
    }
    if (t > 0) {
        uch* vout = vbf + (size_t)(t - 1) * VTEN + ((size_t)b * CC + c0) * VROW;
        const int cr = tid >> 2, nq = (tid & 3) * 16;
        float* row = lt[cr];
        uint4 y = { pk4fp8(row[nq+0], row[nq+1], row[nq+2], row[nq+3]),
                    pk4fp8(row[nq+4], row[nq+5], row[nq+6], row[nq+7]),
                    pk4fp8(row[nq+8], row[nq+9], row[nq+10], row[nq+11]),
                    pk4fp8(row[nq+12], row[nq+13], row[nq+14], row[nq+15]) };
        *(uint4*)&vout[(size_t)cr * VROW + n0 + nq] = y;
        if (xt == 48) {
            uint4 z4 = {0u, 0u, 0u, 0u};
            *(uint4*)&vout[(size_t)cr * VROW + 3136 + (tid & 3) * 16] = z4;
        }
    }
}

// ---------------- ssq -> inv; t=0 slots pre-scaled by log2(e) for exp2 epilogue ----------------
__global__ void rsqrt_k(float* __restrict__ v) {
    int g = blockIdx.x * 256 + threadIdx.x;
    if (g < 3 * BBATCH * NN) {
        float r = 1.0f / fmaxf(sqrtf(v[g]), 1e-12f);
        if (g < BBATCH * NN) r *= 1.44269504088896f;   // fold log2e into inv1
        v[g] = r;
    }
}

// ---------------- gemmA: v19 BK=64 dbuf loop + lean epilogue ----------------
__global__ __launch_bounds__(256) void gemmA_k(const uch* __restrict__ prep,
        const float* __restrict__ inv, uch* __restrict__ P, size_t PBRel,
        float* __restrict__ den, int cbt, int rowcap) {
    __shared__ __align__(16) uch sm[32768];       // dbuf 2x16KB; PT8 [128][144] aliases
    uch* PT8 = sm;
    const int tid = threadIdx.x, w = tid >> 6, l = tid & 63;
    const int mt = blockIdx.x % 25, ntl = blockIdx.x / 25;
    const int b = blockIdx.y, br = blockIdx.z;
    const int n0 = (cbt + ntl) * 128, m0 = mt * 128;
    const uch* qT = prep + (size_t)b * NN * CC;
    const uch* kT = prep + (size_t)(1 + br) * TEN_ELE + (size_t)b * NN * CC;
    const int srow = l >> 2, c4p = l & 3;
    const int g = l >> 4, li = l & 15, nh = w & 1, mh = w >> 1;
    f32x4 acc[4][4];
#pragma unroll
    for (int i = 0; i < 4; ++i)
#pragma unroll
        for (int j = 0; j < 4; ++j) acc[i][j] = (f32x4){0.f, 0.f, 0.f, 0.f};

    auto stageA = [&](int kk, int bb) {
        int c0k = kk * 64;
        uch* dst = sm + bb * 16384;
#pragma unroll
        for (int i = 0; i < 2; ++i) {
            int rowT = i * 64 + w * 16 + srow;
            int rA = n0 + rowT; rA = rA < NN ? rA : NN - 1;
            int rB = m0 + rowT; rB = rB < NN ? rB : NN - 1;
            int co = (c4p ^ ((rowT >> 1) & 3)) << 4;
            gl_lds16(qT + (size_t)rA * CC + c0k + co, dst + i * 4096 + w * 1024);
            gl_lds16(kT + (size_t)rB * CC + c0k + co, dst + 8192 + i * 4096 + w * 1024);
        }
    };

    stageA(0, 0);
    __syncthreads();

    for (int kk = 0; kk < 8; ++kk) {
        int cur = kk & 1;
        if (kk < 7) stageA(kk + 1, cur ^ 1);
        const uch* smc = sm + cur * 16384;
#pragma unroll
        for (int ks = 0; ks < 2; ++ks) {
            long af[4], bf[4];
            int kc = ks * 2 + (g >> 1);
#pragma unroll
            for (int i = 0; i < 4; ++i) {
                int rA = nh * 64 + i * 16 + li;
                af[i] = *(const long*)(smc + rA * 64 +
                        (((kc ^ ((rA >> 1) & 3)) << 4) | ((g & 1) << 3)));
                int rB = mh * 64 + i * 16 + li;
                bf[i] = *(const long*)(smc + 8192 + rB * 64 +
                        (((kc ^ ((rB >> 1) & 3)) << 4) | ((g & 1) << 3)));
            }
            __builtin_amdgcn_s_setprio(1);
#pragma unroll
            for (int i = 0; i < 4; ++i)
#pragma unroll
                for (int j = 0; j < 4; ++j)
                    acc[i][j] = __builtin_amdgcn_mfma_f32_16x16x32_fp8_fp8(af[i], bf[j], acc[i][j], 0, 0, 0);
            __builtin_amdgcn_s_setprio(0);
        }
        __syncthreads();                           // reads done + staged loads drained
    }
    // ---- lean epilogue: exp2 -> PT8 (fp8) + den-from-regs; pure-copy bounce ----
    const float* i1p = inv + (size_t)b * NN;                       // includes log2e
    const float* ikp = inv + (size_t)(1 + br) * (BBATCH * NN) + (size_t)b * NN;
    float ikv[4], i1v[4][4];
#pragma unroll
    for (int j = 0; j < 4; ++j) {
        int m = m0 + mh * 64 + j * 16 + li;
        ikv[j] = ikp[m < NN ? m : NN - 1];
    }
#pragma unroll
    for (int i = 0; i < 4; ++i)
#pragma unroll
        for (int r = 0; r < 4; ++r) {
            int n = n0 + nh * 64 + i * 16 + 4 * g + r;
            i1v[i][r] = -i1p[n < NN ? n : NN - 1];
        }
    const int rowlim = (NN - n0) < 128 ? (NN - n0) : 128;
    const bool mvalid = (m0 + mh * 64) < NN;       // wave-uniform (NN % 64 == 0)
    float rsum[4][4];
#pragma unroll
    for (int i = 0; i < 4; ++i)
#pragma unroll
        for (int r = 0; r < 4; ++r) rsum[i][r] = 0.f;

#pragma unroll
    for (int i = 0; i < 4; ++i) {
        int rowb = nh * 64 + i * 16 + 4 * g;
#pragma unroll
        for (int j = 0; j < 4; ++j) {
            int col = mh * 64 + j * 16 + li;
            float e0 = exp2f(acc[i][j][0] * i1v[i][0] * ikv[j]);
            float e1 = exp2f(acc[i][j][1] * i1v[i][1] * ikv[j]);
            float e2 = exp2f(acc[i][j][2] * i1v[i][2] * ikv[j]);
            float e3 = exp2f(acc[i][j][3] * i1v[i][3] * ikv[j]);
            if (mvalid) {
                rsum[i][0] += e0; rsum[i][1] += e1;
                rsum[i][2] += e2; rsum[i][3] += e3;
            }
            unsigned p01 = __builtin_amdgcn_cvt_pk_fp8_f32(e0, e1, 0u, false);
            unsigned p23 = __builtin_amdgcn_cvt_pk_fp8_f32(e2, e3, 0u, false);
            PT8[(rowb + 0) * 144 + col] = (uch)(p01 & 0xff);
            PT8[(rowb + 1) * 144 + col] = (uch)((p01 >> 8) & 0xff);
            PT8[(rowb + 2) * 144 + col] = (uch)(p23 & 0xff);
            PT8[(rowb + 3) * 144 + col] = (uch)((p23 >> 8) & 0xff);
        }
    }
    float* denp = den + (size_t)(br * BBATCH + b) * NN;
    if (mvalid) {
#pragma unroll
        for (int i = 0; i < 4; ++i)
#pragma unroll
            for (int r = 0; r < 4; ++r) {
                float s = rsum[i][r];
                s += __shfl_xor(s, 1); s += __shfl_xor(s, 2);
                s += __shfl_xor(s, 4); s += __shfl_xor(s, 8);
                int row = nh * 64 + i * 16 + 4 * g + r;
                if (li == 0 && row < rowlim) atomicAdd(&denp[n0 + row], s);
            }
    }
    __syncthreads();
    // pure-copy bounce: 4 passes of 16B chunks
    uch* Pg = P + (size_t)br * PBRel + ((size_t)b * rowcap + (size_t)ntl * 128) * VROW;
    const int ck16 = tid & 7, rb32 = tid >> 3;
    const int ckmax = ((NN - m0) < 128 ? (NN - m0) : 128) >> 4;
#pragma unroll
    for (int pass = 0; pass < 4; ++pass) {
        int rr = rb32 + pass * 32;
        uint4 v = *(const uint4*)&PT8[rr * 144 + ck16 * 16];
        if (ck16 >= ckmax) v = (uint4){0u, 0u, 0u, 0u};
        if (rr < rowlim)
            *(uint4*)&Pg[(size_t)rr * VROW + m0 + ck16 * 16] = v;
    }
}

// ---------------- gemmB: 128² tile + 2-phase dbuf pipeline (proven v17, untouched) ----------------
__global__ __launch_bounds__(256) void gemmB_k(const uch* __restrict__ vbf,
        const uch* __restrict__ P, size_t PBRel, const float* __restrict__ den,
        const float* __restrict__ fm1, float* __restrict__ out, int cbt, int rowcap) {
    __shared__ __align__(16) uch sm[65536];       // 2 x { V 16KB | P 16KB }
    const int tid = threadIdx.x, w = tid >> 6, l = tid & 63;
    const int ct = blockIdx.x & 3, ntl = blockIdx.x >> 2;
    const int b = blockIdx.y;
    const int c0 = ct * 128, n0 = (cbt + ntl) * 128;
    const int lr8 = l >> 3, c4p = l & 7;
    const int g = l >> 4, li = l & 15, ch = w & 1, nh = w >> 1;
    const float* d2p = den + (size_t)b * NN;
    const float* d3p = den + (size_t)(BBATCH + b) * NN;
    float d2[4], d3[4];
#pragma unroll
    for (int j = 0; j < 4; ++j) {
        int n = n0 + nh * 64 + j * 16 + li;
        int nc = n < NN ? n : NN - 1;
        d2[j] = d2p[nc]; d3[j] = d3p[nc];
    }
    f32x4 acc[4][4];
#pragma unroll
    for (int i = 0; i < 4; ++i)
#pragma unroll
        for (int j = 0; j < 4; ++j) acc[i][j] = (f32x4){0.f, 0.f, 0.f, 0.f};
    const int rowclamp = (NN - 1 - n0) < 127 ? (NN - 1 - n0) : 127;

    auto stage = [&](int gk, int bb) {
        int brr = gk < 25 ? 1 : 0;                 // P3 first, ratio-fold, then P2
        int km = gk < 25 ? gk : gk - 25;
        const uch* vA = vbf + (size_t)brr * VTEN + (size_t)b * CC * VROW;
        const uch* pB = P + (size_t)brr * PBRel + ((size_t)b * rowcap + (size_t)ntl * 128) * VROW;
        int mm0 = km * 128;
        uch* dst = sm + bb * 32768;
#pragma unroll
        for (int i = 0; i < 4; ++i) {
            int rowT = i * 32 + w * 8 + lr8;
            int co = (c4p ^ (rowT & 7)) << 4;
            int rloc = rowT < rowclamp ? rowT : rowclamp;
            gl_lds16(vA + (size_t)(c0 + rowT) * VROW + mm0 + co, dst + i * 4096 + w * 1024);
            gl_lds16(pB + (size_t)rloc * VROW + mm0 + co, dst + 16384 + i * 4096 + w * 1024);
        }
    };

    stage(0, 0);
    __syncthreads();

    for (int gk = 0; gk < 50; ++gk) {
        int cur = gk & 1;
        if (gk < 49) stage(gk + 1, cur ^ 1);
        const uch* smc = sm + cur * 32768;
#pragma unroll
        for (int ks = 0; ks < 4; ++ks) {
            long af[4], bf[4];
#pragma unroll
            for (int i = 0; i < 4; ++i) {
                int rA = ch * 64 + i * 16 + li;
                af[i] = *(const long*)(smc + rA * 128 +
                        ((((2 * ks + (g >> 1)) ^ (rA & 7)) << 4) | ((g & 1) << 3)));
                int rB = nh * 64 + i * 16 + li;
                bf[i] = *(const long*)(smc + 16384 + rB * 128 +
                        ((((2 * ks + (g >> 1)) ^ (rB & 7)) << 4) | ((g & 1) << 3)));
            }
#pragma unroll
            for (int i = 0; i < 4; ++i)
#pragma unroll
                for (int j = 0; j < 4; ++j)
                    acc[i][j] = __builtin_amdgcn_mfma_f32_16x16x32_fp8_fp8(af[i], bf[j], acc[i][j], 0, 0, 0);
        }
        if (gk == 24) {
#pragma unroll
            for (int j = 0; j < 4; ++j) {
                float ratio = d2[j] / fmaxf(d3[j], 1e-30f);
#pragma unroll
                for (int i = 0; i < 4; ++i)
#pragma unroll
                    for (int r = 0; r < 4; ++r) acc[i][j][r] *= ratio;
            }
        }
        __syncthreads();
    }
    const float* fb = fm1 + (size_t)b * CC * NN;
    float* ob = out + (size_t)b * CC * NN;
#pragma unroll
    for (int j = 0; j < 4; ++j) {
        int n = n0 + nh * 64 + j * 16 + li;
        if (n < NN) {
            float s2 = 0.001f / fmaxf(d2[j], 1e-30f);
#pragma unroll
            for (int i = 0; i < 4; ++i) {
                int cc = c0 + ch * 64 + i * 16 + 4 * g;
#pragma unroll
                for (int r = 0; r < 4; ++r) {
                    size_t o = (size_t)(cc + r) * NN + n;
                    ob[o] = fb[o] + s2 * acc[i][j][r];
                }
            }
        }
    }
}

// ================= fallback (proven R5 fused kernel, used only if ws too small) ===============
__global__ void norms_k(const float* __restrict__ f1, const float* __restrict__ f2,
                        const float* __restrict__ f3, float* __restrict__ inv) {
    int gg = blockIdx.x * 256 + threadIdx.x;
    int t = gg / (BBATCH * NN);
    int r = gg - t * (BBATCH * NN);
    int b = r / NN;
    int n = r - b * NN;
    const float* f = (t == 0) ? f1 : (t == 1) ? f2 : f3;
    const float* p = f + (size_t)b * CC * NN + n;
    float ss = 0.f;
#pragma unroll 8
    for (int c = 0; c < CC; ++c) { float x = p[(size_t)c * NN]; ss = fmaf(x, x, ss); }
    inv[gg] = 1.0f / fmaxf(sqrtf(ss), 1e-12f);
}
__global__ void init_k(const float4* __restrict__ src, float4* __restrict__ dst) {
    int gg = blockIdx.x * 256 + threadIdx.x;
    dst[gg] = src[gg];
}
static constexpr int FKTOFF = 16384, FVBASE = 32768, FVOFF = 20480, FPBASE = 73728, FVSTR = 40;
__launch_bounds__(512, 2)
__global__ void attn_fb_k(const float* __restrict__ fq_all, const float* __restrict__ f2_all,
                          const float* __restrict__ f3_all, const float* __restrict__ invws,
                          float* __restrict__ out) {
    __shared__ __align__(16) ush smem[2 * 16384 + 2 * 20480 + 64 * 40];
    __shared__ float denbuf[8][16];
    ush* pp = smem + FPBASE;
    ush* qstage = smem;
    const int tid = threadIdx.x, w = tid >> 6, l = tid & 63;
    const int u = blockIdx.x, batch = u & 7, unit = u >> 3, br = unit & 1, qt = unit >> 1;
    const int n0 = qt * 64;
    const float* fq = fq_all + (size_t)batch * CC * NN;
    const float* fk = (br ? f3_all : f2_all) + (size_t)batch * CC * NN;
    const float* inv1 = invws + batch * NN;
    const float* invk = invws + (1 + br) * (BBATCH * NN) + batch * NN;
    {
        int n = tid & 63, grp = tid >> 6;
        float s = -inv1[n0 + n];
        const float* src = fq + n0 + n;
        int sw = (n & 7) << 3;
#pragma unroll 4
        for (int ssi = 0; ssi < 16; ++ssi) {
            int cb = grp * 4 + 32 * ssi; int b0 = cb * NN;
            uint2 y = { pkbf(src[b0] * s, src[b0 + NN] * s),
                        pkbf(src[b0 + 2 * NN] * s, src[b0 + 3 * NN] * s) };
            *(uint2*)&qstage[n * 512 + (cb ^ sw)] = y;
        }
    }
    __syncthreads();
    short8 qf[16];
    {
        int nQ = 16 * (w & 3) + (l & 15);
        int sw = (nQ & 7) << 3;
#pragma unroll
        for (int ks = 0; ks < 16; ++ks)
            qf[ks] = *(const short8*)&qstage[nQ * 512 + ((ks * 32 + ((l >> 4) << 3)) ^ sw)];
    }
    __syncthreads();
    auto stage = [&](int it, int bb2) {
        int m = tid & 31, grp = tid >> 5;
        int m0 = it * 32;
        float sk = invk[m0 + m];
        const float* src = fk + m0 + m;
        ush* KT = smem + (bb2 ? FKTOFF : 0);
        ush* V = smem + FVBASE + (bb2 ? FVOFF : 0);
        int swm = (m & 7) << 3;
        float xb[32];
#pragma unroll
        for (int ssi = 0; ssi < 8; ++ssi) {
            int b0 = (grp * 4 + 64 * ssi) * NN;
            xb[ssi * 4 + 0] = src[b0]; xb[ssi * 4 + 1] = src[b0 + NN];
            xb[ssi * 4 + 2] = src[b0 + 2 * NN]; xb[ssi * 4 + 3] = src[b0 + 3 * NN];
        }
#pragma unroll
        for (int ssi = 0; ssi < 8; ++ssi) {
            int cb = grp * 4 + 64 * ssi;
            uint2 y = { pkbf(xb[ssi * 4 + 0] * sk, xb[ssi * 4 + 1] * sk),
                        pkbf(xb[ssi * 4 + 2] * sk, xb[ssi * 4 + 3] * sk) };
            *(uint2*)&KT[m * 512 + (cb ^ swm)] = y;
            ush* vb = &V[cb * FVSTR + m];
            vb[0] = sbf(xb[ssi * 4 + 0]); vb[FVSTR] = sbf(xb[ssi * 4 + 1]);
            vb[2 * FVSTR] = sbf(xb[ssi * 4 + 2]); vb[3 * FVSTR] = sbf(xb[ssi * 4 + 3]);
        }
    };
    f32x4 acc[8][2];
#pragma unroll
    for (int ci = 0; ci < 8; ++ci) { acc[ci][0] = (f32x4){0,0,0,0}; acc[ci][1] = (f32x4){0,0,0,0}; }
    float den_part = 0.f;
    stage(0, 0);
    const int mt = w >> 2, nt = w & 3, np = w & 1, cg = w >> 1;
    const int g = l >> 4, li = l & 15;
    const int mA = 16 * mt + li, swA = (mA & 7) << 3, nP = 16 * nt + li;
    for (int it = 0; it < 98; ++it) {
        int bb2 = it & 1;
        __syncthreads();
        f32x4 sacc = (f32x4){0,0,0,0};
        const ush* KT = smem + (bb2 ? FKTOFF : 0);
#pragma unroll
        for (int ks = 0; ks < 16; ++ks) {
            short8 af = *(const short8*)&KT[mA * 512 + ((ks * 32 + (g << 3)) ^ swA)];
            sacc = __builtin_amdgcn_mfma_f32_16x16x32_bf16(af, qf[ks], sacc, 0, 0, 0);
        }
        float p0 = __expf(sacc[0]), p1 = __expf(sacc[1]);
        float p2 = __expf(sacc[2]), p3 = __expf(sacc[3]);
        den_part += (p0 + p1) + (p2 + p3);
        uint2 pw = { pkbf(p0, p1), pkbf(p2, p3) };
        *(uint2*)&pp[nP * FVSTR + 16 * mt + 4 * g] = pw;
        if (it != 97) stage(it + 1, bb2 ^ 1);
        __syncthreads();
        const ush* V = smem + FVBASE + (bb2 ? FVOFF : 0);
        short8 bf0 = *(const short8*)&pp[(32 * np + li) * FVSTR + (g << 3)];
        short8 bf1 = *(const short8*)&pp[(32 * np + 16 + li) * FVSTR + (g << 3)];
        const ush* vbase = &V[(128 * cg + li) * FVSTR + (g << 3)];
#pragma unroll
        for (int ci = 0; ci < 8; ++ci) {
            short8 af = *(const short8*)&vbase[ci * 16 * FVSTR];
            acc[ci][0] = __builtin_amdgcn_mfma_f32_16x16x32_bf16(af, bf0, acc[ci][0], 0, 0, 0);
            acc[ci][1] = __builtin_amdgcn_mfma_f32_16x16x32_bf16(af, bf1, acc[ci][1], 0, 0, 0);
        }
    }
    den_part += __shfl_xor(den_part, 16);
    den_part += __shfl_xor(den_part, 32);
    if (l < 16) denbuf[w][l] = den_part;
    __syncthreads();
    float sc0 = 0.001f / (denbuf[2 * np + 0][li] + denbuf[4 + 2 * np + 0][li]);
    float sc1 = 0.001f / (denbuf[2 * np + 1][li] + denbuf[4 + 2 * np + 1][li]);
    float* op = out + (size_t)batch * CC * NN + n0;
    const int nc0 = 16 * (2 * np + 0) + li, nc1 = 16 * (2 * np + 1) + li;
#pragma unroll
    for (int ci = 0; ci < 8; ++ci) {
        int cbase = 16 * (8 * cg + ci) + 4 * g;
#pragma unroll
        for (int r = 0; r < 4; ++r) {
            atomicAdd(&op[(size_t)(cbase + r) * NN + nc0], acc[ci][0][r] * sc0);
            atomicAdd(&op[(size_t)(cbase + r) * NN + nc1], acc[ci][1][r] * sc1);
        }
    }
}

extern "C" void kernel_launch(void* const* d_in, const int* in_sizes, int n_in,
                              void* d_out, int out_size, void* d_ws, size_t ws_size,
                              hipStream_t stream) {
    (void)in_sizes; (void)n_in; (void)out_size;
    const float* f1 = (const float*)d_in[0];
    const float* f2 = (const float*)d_in[1];
    const float* f3 = (const float*)d_in[2];
    float* out = (float*)d_out;
    char* ws = (char*)d_ws;

    if (ws_size >= P_OFS + PER_TILE) {
        size_t tmax = (ws_size - P_OFS) / PER_TILE;
        int T = tmax < 25 ? (int)tmax : 25;
        int rowcap = T * 128;
        size_t PBRel = (size_t)BBATCH * rowcap * VROW;   // bytes per branch
        float* ssq = (float*)(ws + INV_OFS);
        float* den = (float*)(ws + DEN_OFS);
        uch* prep = (uch*)(ws + PREP_OFS);
        uch* vbf = (uch*)(ws + VBF_OFS);
        uch* P = (uch*)(ws + P_OFS);
        hipMemsetAsync(ws, 0, DEN_OFS + 200704, stream);
        prepT_k<<<dim3(49, 8, 24), 256, 0, stream>>>(f1, f2, f3, ssq, prep, vbf);
        rsqrt_k<<<294, 256, 0, stream>>>(ssq);
        for (int cbt = 0; cbt < 25; ) {
            int t = (25 - cbt) < T ? (25 - cbt) : T;
            gemmA_k<<<dim3(25 * t, 8, 2), 256, 0, stream>>>(prep, ssq, P, PBRel, den, cbt, rowcap);
            gemmB_k<<<dim3(4 * t, 8), 256, 0, stream>>>(vbf, P, PBRel, den, f1, out, cbt, rowcap);
            cbt += t;
        }
    } else {
        float* inv = (float*)(ws + INV_OFS);
        norms_k<<<294, 256, 0, stream>>>(f1, f2, f3, inv);
        init_k<<<12544, 256, 0, stream>>>((const float4*)f1, (float4*)out);
        attn_fb_k<<<784, 512, 0, stream>>>(f1, f2, f3, inv, out);
    }
}

// Round 22
// 387.533 us; speedup vs baseline: 1.4164x; 1.2828x over previous
//
// v22 — exact R19 kernels + ONE change: nontemporal P stores in gemmA (protect L3 for prep)
#include <hip/hip_runtime.h>
#include <hip/hip_bf16.h>

#define NN 3136
#define CC 512
#define BBATCH 8

typedef unsigned short ush;
typedef unsigned char uch;
typedef __attribute__((ext_vector_type(4))) float f32x4;
typedef __attribute__((ext_vector_type(8))) short short8;

static __device__ __forceinline__ unsigned int pkbf(float a, float b) {
    union { __hip_bfloat162 h; unsigned int u; } v;
    v.h = __float22bfloat162_rn(make_float2(a, b));
    return v.u;
}
static __device__ __forceinline__ ush sbf(float a) {
    union { __hip_bfloat16 h; ush u; } v;
    v.h = __float2bfloat16(a);
    return v.u;
}
static __device__ __forceinline__ unsigned int pk4fp8(float a, float b, float c, float d) {
    unsigned int r = 0;
    r = __builtin_amdgcn_cvt_pk_fp8_f32(a, b, r, false);
    r = __builtin_amdgcn_cvt_pk_fp8_f32(c, d, r, true);
    return r;
}
static __device__ __forceinline__ void gl_lds16(const void* g, void* l) {
    __builtin_amdgcn_global_load_lds((const __attribute__((address_space(1))) void*)g,
                                     (__attribute__((address_space(3))) void*)l, 16, 0, 0);
}

// ---- ws layout (bytes) ----
static constexpr size_t TEN_ELE  = (size_t)BBATCH * NN * CC;   // fp8 bytes
static constexpr size_t VROW     = 3200;
static constexpr size_t VTEN     = (size_t)BBATCH * CC * VROW;
static constexpr size_t INV_OFS  = 0;
static constexpr size_t DEN_OFS  = 301056;
static constexpr size_t PREP_OFS = 501760;
static constexpr size_t VBF_OFS  = PREP_OFS + 3 * TEN_ELE;
static constexpr size_t P_OFS    = VBF_OFS + 2 * VTEN;
static constexpr size_t PER_TILE = 2ull * BBATCH * 128 * VROW;

// ---------------- prepT (unchanged) ----------------
__global__ void prepT_k(const float* __restrict__ f1, const float* __restrict__ f2,
                        const float* __restrict__ f3, float* __restrict__ ssq,
                        uch* __restrict__ prep, uch* __restrict__ vbf) {
    __shared__ float lt[64][65];
    const int tid = threadIdx.x;
    const int xt = blockIdx.x, yc = blockIdx.y, z = blockIdx.z;
    const int t = z >> 3, b = z & 7;
    const float* f = (t == 0) ? f1 : (t == 1) ? f2 : f3;
    const int n0 = xt * 64, c0 = yc * 64;
    const float* src = f + (size_t)b * CC * NN + (size_t)c0 * NN + n0;
    {
        const int col4 = (tid & 15) * 4, rw = tid >> 4;
#pragma unroll
        for (int p = 0; p < 4; ++p) {
            int row = p * 16 + rw;
            f32x4 v = *(const f32x4*)&src[(size_t)row * NN + col4];
            lt[row][col4 + 0] = v[0]; lt[row][col4 + 1] = v[1];
            lt[row][col4 + 2] = v[2]; lt[row][col4 + 3] = v[3];
        }
    }
    __syncthreads();
    {
        uch* dst = prep + (size_t)t * TEN_ELE + ((size_t)b * NN + n0) * CC + c0;
        float* sq = ssq + (size_t)t * BBATCH * NN + (size_t)b * NN + n0;
        const int cchunk = tid & 7, nr = tid >> 3;
#pragma unroll
        for (int p = 0; p < 2; ++p) {
            int n = p * 32 + nr;
            float x0 = lt[cchunk * 8 + 0][n], x1 = lt[cchunk * 8 + 1][n];
            float x2 = lt[cchunk * 8 + 2][n], x3 = lt[cchunk * 8 + 3][n];
            float x4 = lt[cchunk * 8 + 4][n], x5 = lt[cchunk * 8 + 5][n];
            float x6 = lt[cchunk * 8 + 6][n], x7 = lt[cchunk * 8 + 7][n];
            uint2 y = { pk4fp8(x0, x1, x2, x3), pk4fp8(x4, x5, x6, x7) };
            *(uint2*)&dst[(size_t)n * CC + cchunk * 8] = y;
            float s = x0*x0 + x1*x1 + x2*x2 + x3*x3 + x4*x4 + x5*x5 + x6*x6 + x7*x7;
            s += __shfl_xor(s, 1); s += __shfl_xor(s, 2); s += __shfl_xor(s, 4);
            if (cchunk == 0) atomicAdd(&sq[n], s);
        }
    }
    if (t > 0) {
        uch* vout = vbf + (size_t)(t - 1) * VTEN + ((size_t)b * CC + c0) * VROW;
        const int cr = tid >> 2, nq = (tid & 3) * 16;
        float* row = lt[cr];
        uint4 y = { pk4fp8(row[nq+0], row[nq+1], row[nq+2], row[nq+3]),
                    pk4fp8(row[nq+4], row[nq+5], row[nq+6], row[nq+7]),
                    pk4fp8(row[nq+8], row[nq+9], row[nq+10], row[nq+11]),
                    pk4fp8(row[nq+12], row[nq+13], row[nq+14], row[nq+15]) };
        *(uint4*)&vout[(size_t)cr * VROW + n0 + nq] = y;
        if (xt == 48) {
            uint4 z4 = {0u, 0u, 0u, 0u};
            *(uint4*)&vout[(size_t)cr * VROW + 3136 + (tid & 3) * 16] = z4;
        }
    }
}

// ---------------- ssq -> inv ----------------
__global__ void rsqrt_k(float* __restrict__ v) {
    int g = blockIdx.x * 256 + threadIdx.x;
    if (g < 3 * BBATCH * NN) v[g] = 1.0f / fmaxf(sqrtf(v[g]), 1e-12f);
}

// ---------------- gemmA: BK=64 dbuf (8 phases), 4 WG/CU; epilogue exp; P(nt) + den ----------------
__global__ __launch_bounds__(256) void gemmA_k(const uch* __restrict__ prep,
        const float* __restrict__ inv, uch* __restrict__ P, size_t PBRel,
        float* __restrict__ den, int cbt, int rowcap) {
    __shared__ __align__(16) uch sm[34816];       // dbuf 2x16KB; PT bf16 128x136 aliases all
    ush* PT = (ush*)sm;
    const int tid = threadIdx.x, w = tid >> 6, l = tid & 63;
    const int mt = blockIdx.x % 25, ntl = blockIdx.x / 25;
    const int b = blockIdx.y, br = blockIdx.z;
    const int n0 = (cbt + ntl) * 128, m0 = mt * 128;
    const uch* qT = prep + (size_t)b * NN * CC;
    const uch* kT = prep + (size_t)(1 + br) * TEN_ELE + (size_t)b * NN * CC;
    const int srow = l >> 2, c4p = l & 3;         // staging: 16 rows/wave, 4x16B chunks/row
    const int g = l >> 4, li = l & 15, nh = w & 1, mh = w >> 1;
    f32x4 acc[4][4];
#pragma unroll
    for (int i = 0; i < 4; ++i)
#pragma unroll
        for (int j = 0; j < 4; ++j) acc[i][j] = (f32x4){0.f, 0.f, 0.f, 0.f};

    auto stageA = [&](int kk, int bb) {
        int c0k = kk * 64;
        uch* dst = sm + bb * 16384;
#pragma unroll
        for (int i = 0; i < 2; ++i) {
            int rowT = i * 64 + w * 16 + srow;    // 0..127
            int rA = n0 + rowT; rA = rA < NN ? rA : NN - 1;
            int rB = m0 + rowT; rB = rB < NN ? rB : NN - 1;
            int co = (c4p ^ ((rowT >> 1) & 3)) << 4;
            gl_lds16(qT + (size_t)rA * CC + c0k + co, dst + i * 4096 + w * 1024);
            gl_lds16(kT + (size_t)rB * CC + c0k + co, dst + 8192 + i * 4096 + w * 1024);
        }
    };

    stageA(0, 0);
    __syncthreads();                               // buf0 ready

    for (int kk = 0; kk < 8; ++kk) {
        int cur = kk & 1;
        if (kk < 7) stageA(kk + 1, cur ^ 1);       // prefetch next phase into other buffer
        const uch* smc = sm + cur * 16384;
#pragma unroll
        for (int ks = 0; ks < 2; ++ks) {
            long af[4], bf[4];
            int kc = ks * 2 + (g >> 1);
#pragma unroll
            for (int i = 0; i < 4; ++i) {
                int rA = nh * 64 + i * 16 + li;
                af[i] = *(const long*)(smc + rA * 64 +
                        (((kc ^ ((rA >> 1) & 3)) << 4) | ((g & 1) << 3)));
                int rB = mh * 64 + i * 16 + li;
                bf[i] = *(const long*)(smc + 8192 + rB * 64 +
                        (((kc ^ ((rB >> 1) & 3)) << 4) | ((g & 1) << 3)));
            }
#pragma unroll
            for (int i = 0; i < 4; ++i)
#pragma unroll
                for (int j = 0; j < 4; ++j)
                    acc[i][j] = __builtin_amdgcn_mfma_f32_16x16x32_fp8_fp8(af[i], bf[j], acc[i][j], 0, 0, 0);
        }
        __syncthreads();                           // reads done + staged loads drained
    }
    // epilogue: s = acc * (-inv1[n]) * invk[m]; exp; PT bounce; fp8 stores (nt) + den
    const float* i1p = inv + (size_t)b * NN;
    const float* ikp = inv + (size_t)(1 + br) * (BBATCH * NN) + (size_t)b * NN;
    float ikv[4], i1v[4][4];
#pragma unroll
    for (int j = 0; j < 4; ++j) {
        int m = m0 + mh * 64 + j * 16 + li;
        ikv[j] = ikp[m < NN ? m : NN - 1];
    }
#pragma unroll
    for (int i = 0; i < 4; ++i)
#pragma unroll
        for (int r = 0; r < 4; ++r) {
            int n = n0 + nh * 64 + i * 16 + 4 * g + r;
            i1v[i][r] = -i1p[n < NN ? n : NN - 1];
        }
#pragma unroll
    for (int i = 0; i < 4; ++i)
#pragma unroll
        for (int j = 0; j < 4; ++j) {
            int col = mh * 64 + j * 16 + li;
#pragma unroll
            for (int r = 0; r < 4; ++r) {
                int row = nh * 64 + i * 16 + 4 * g + r;
                PT[row * 136 + col] = sbf(__expf(acc[i][j][r] * i1v[i][r] * ikv[j]));
            }
        }
    __syncthreads();
    const int rowlim = (NN - n0) < 128 ? (NN - n0) : 128;
    const int mchunks = (NN - m0) < 128 ? ((NN - m0) >> 3) : 16;
    uch* Pg = P + (size_t)br * PBRel + ((size_t)b * rowcap + (size_t)ntl * 128) * VROW;
    float* denp = den + (size_t)(br * BBATCH + b) * NN;
    const int ck = tid & 15, rbase = tid >> 4;
#pragma unroll
    for (int pass = 0; pass < 8; ++pass) {
        int rr = rbase + pass * 16;
        uint4 v = *(const uint4*)&PT[rr * 136 + ck * 8];
        unsigned vv[4] = { v.x, v.y, v.z, v.w };
        float fv[8];
#pragma unroll
        for (int q = 0; q < 4; ++q) {
            union { unsigned u; float f; } lo, hi;
            lo.u = vv[q] << 16; hi.u = vv[q] & 0xffff0000u;
            fv[2 * q] = lo.f; fv[2 * q + 1] = hi.f;
        }
        float s = 0.f;
        if (ck < mchunks)
            s = ((fv[0] + fv[1]) + (fv[2] + fv[3])) + ((fv[4] + fv[5]) + (fv[6] + fv[7]));
        s += __shfl_xor(s, 1); s += __shfl_xor(s, 2);
        s += __shfl_xor(s, 4); s += __shfl_xor(s, 8);
        if (ck == 0 && rr < rowlim) atomicAdd(&denp[n0 + rr], s);
        if (rr < rowlim) {
            uint2 pv = {0u, 0u};
            if (ck < mchunks) {
                pv.x = pk4fp8(fv[0], fv[1], fv[2], fv[3]);
                pv.y = pk4fp8(fv[4], fv[5], fv[6], fv[7]);
            }
            unsigned long long pu = ((unsigned long long)pv.y << 32) | (unsigned long long)pv.x;
            __builtin_nontemporal_store(pu,
                (unsigned long long*)&Pg[(size_t)rr * VROW + m0 + ck * 8]);
        }
    }
}

// ---------------- gemmB: 128² tile + 2-phase dbuf pipeline (proven v17, untouched) ----------------
__global__ __launch_bounds__(256) void gemmB_k(const uch* __restrict__ vbf,
        const uch* __restrict__ P, size_t PBRel, const float* __restrict__ den,
        const float* __restrict__ fm1, float* __restrict__ out, int cbt, int rowcap) {
    __shared__ __align__(16) uch sm[65536];       // 2 x { V 16KB | P 16KB }
    const int tid = threadIdx.x, w = tid >> 6, l = tid & 63;
    const int ct = blockIdx.x & 3, ntl = blockIdx.x >> 2;
    const int b = blockIdx.y;
    const int c0 = ct * 128, n0 = (cbt + ntl) * 128;
    const int lr8 = l >> 3, c4p = l & 7;
    const int g = l >> 4, li = l & 15, ch = w & 1, nh = w >> 1;
    const float* d2p = den + (size_t)b * NN;
    const float* d3p = den + (size_t)(BBATCH + b) * NN;
    float d2[4], d3[4];
#pragma unroll
    for (int j = 0; j < 4; ++j) {
        int n = n0 + nh * 64 + j * 16 + li;
        int nc = n < NN ? n : NN - 1;
        d2[j] = d2p[nc]; d3[j] = d3p[nc];
    }
    f32x4 acc[4][4];
#pragma unroll
    for (int i = 0; i < 4; ++i)
#pragma unroll
        for (int j = 0; j < 4; ++j) acc[i][j] = (f32x4){0.f, 0.f, 0.f, 0.f};
    const int rowclamp = (NN - 1 - n0) < 127 ? (NN - 1 - n0) : 127;

    auto stage = [&](int gk, int bb) {
        int brr = gk < 25 ? 1 : 0;                 // P3 first, ratio-fold, then P2
        int km = gk < 25 ? gk : gk - 25;
        const uch* vA = vbf + (size_t)brr * VTEN + (size_t)b * CC * VROW;
        const uch* pB = P + (size_t)brr * PBRel + ((size_t)b * rowcap + (size_t)ntl * 128) * VROW;
        int mm0 = km * 128;
        uch* dst = sm + bb * 32768;
#pragma unroll
        for (int i = 0; i < 4; ++i) {
            int rowT = i * 32 + w * 8 + lr8;
            int co = (c4p ^ (rowT & 7)) << 4;
            int rloc = rowT < rowclamp ? rowT : rowclamp;
            gl_lds16(vA + (size_t)(c0 + rowT) * VROW + mm0 + co, dst + i * 4096 + w * 1024);
            gl_lds16(pB + (size_t)rloc * VROW + mm0 + co, dst + 16384 + i * 4096 + w * 1024);
        }
    };

    stage(0, 0);
    __syncthreads();

    for (int gk = 0; gk < 50; ++gk) {
        int cur = gk & 1;
        if (gk < 49) stage(gk + 1, cur ^ 1);
        const uch* smc = sm + cur * 32768;
#pragma unroll
        for (int ks = 0; ks < 4; ++ks) {
            long af[4], bf[4];
#pragma unroll
            for (int i = 0; i < 4; ++i) {
                int rA = ch * 64 + i * 16 + li;
                af[i] = *(const long*)(smc + rA * 128 +
                        ((((2 * ks + (g >> 1)) ^ (rA & 7)) << 4) | ((g & 1) << 3)));
                int rB = nh * 64 + i * 16 + li;
                bf[i] = *(const long*)(smc + 16384 + rB * 128 +
                        ((((2 * ks + (g >> 1)) ^ (rB & 7)) << 4) | ((g & 1) << 3)));
            }
#pragma unroll
            for (int i = 0; i < 4; ++i)
#pragma unroll
                for (int j = 0; j < 4; ++j)
                    acc[i][j] = __builtin_amdgcn_mfma_f32_16x16x32_fp8_fp8(af[i], bf[j], acc[i][j], 0, 0, 0);
        }
        if (gk == 24) {
#pragma unroll
            for (int j = 0; j < 4; ++j) {
                float ratio = d2[j] / fmaxf(d3[j], 1e-30f);
#pragma unroll
                for (int i = 0; i < 4; ++i)
#pragma unroll
                    for (int r = 0; r < 4; ++r) acc[i][j][r] *= ratio;
            }
        }
        __syncthreads();
    }
    const float* fb = fm1 + (size_t)b * CC * NN;
    float* ob = out + (size_t)b * CC * NN;
#pragma unroll
    for (int j = 0; j < 4; ++j) {
        int n = n0 + nh * 64 + j * 16 + li;
        if (n < NN) {
            float s2 = 0.001f / fmaxf(d2[j], 1e-30f);
#pragma unroll
            for (int i = 0; i < 4; ++i) {
                int cc = c0 + ch * 64 + i * 16 + 4 * g;
#pragma unroll
                for (int r = 0; r < 4; ++r) {
                    size_t o = (size_t)(cc + r) * NN + n;
                    ob[o] = fb[o] + s2 * acc[i][j][r];
                }
            }
        }
    }
}

// ================= fallback (proven R5 fused kernel, used only if ws too small) ===============
__global__ void norms_k(const float* __restrict__ f1, const float* __restrict__ f2,
                        const float* __restrict__ f3, float* __restrict__ inv) {
    int gg = blockIdx.x * 256 + threadIdx.x;
    int t = gg / (BBATCH * NN);
    int r = gg - t * (BBATCH * NN);
    int b = r / NN;
    int n = r - b * NN;
    const float* f = (t == 0) ? f1 : (t == 1) ? f2 : f3;
    const float* p = f + (size_t)b * CC * NN + n;
    float ss = 0.f;
#pragma unroll 8
    for (int c = 0; c < CC; ++c) { float x = p[(size_t)c * NN]; ss = fmaf(x, x, ss); }
    inv[gg] = 1.0f / fmaxf(sqrtf(ss), 1e-12f);
}
__global__ void init_k(const float4* __restrict__ src, float4* __restrict__ dst) {
    int gg = blockIdx.x * 256 + threadIdx.x;
    dst[gg] = src[gg];
}
static constexpr int FKTOFF = 16384, FVBASE = 32768, FVOFF = 20480, FPBASE = 73728, FVSTR = 40;
__launch_bounds__(512, 2)
__global__ void attn_fb_k(const float* __restrict__ fq_all, const float* __restrict__ f2_all,
                          const float* __restrict__ f3_all, const float* __restrict__ invws,
                          float* __restrict__ out) {
    __shared__ __align__(16) ush smem[2 * 16384 + 2 * 20480 + 64 * 40];
    __shared__ float denbuf[8][16];
    ush* pp = smem + FPBASE;
    ush* qstage = smem;
    const int tid = threadIdx.x, w = tid >> 6, l = tid & 63;
    const int u = blockIdx.x, batch = u & 7, unit = u >> 3, br = unit & 1, qt = unit >> 1;
    const int n0 = qt * 64;
    const float* fq = fq_all + (size_t)batch * CC * NN;
    const float* fk = (br ? f3_all : f2_all) + (size_t)batch * CC * NN;
    const float* inv1 = invws + batch * NN;
    const float* invk = invws + (1 + br) * (BBATCH * NN) + batch * NN;
    {
        int n = tid & 63, grp = tid >> 6;
        float s = -inv1[n0 + n];
        const float* src = fq + n0 + n;
        int sw = (n & 7) << 3;
#pragma unroll 4
        for (int ssi = 0; ssi < 16; ++ssi) {
            int cb = grp * 4 + 32 * ssi; int b0 = cb * NN;
            uint2 y = { pkbf(src[b0] * s, src[b0 + NN] * s),
                        pkbf(src[b0 + 2 * NN] * s, src[b0 + 3 * NN] * s) };
            *(uint2*)&qstage[n * 512 + (cb ^ sw)] = y;
        }
    }
    __syncthreads();
    short8 qf[16];
    {
        int nQ = 16 * (w & 3) + (l & 15);
        int sw = (nQ & 7) << 3;
#pragma unroll
        for (int ks = 0; ks < 16; ++ks)
            qf[ks] = *(const short8*)&qstage[nQ * 512 + ((ks * 32 + ((l >> 4) << 3)) ^ sw)];
    }
    __syncthreads();
    auto stage = [&](int it, int bb2) {
        int m = tid & 31, grp = tid >> 5;
        int m0 = it * 32;
        float sk = invk[m0 + m];
        const float* src = fk + m0 + m;
        ush* KT = smem + (bb2 ? FKTOFF : 0);
        ush* V = smem + FVBASE + (bb2 ? FVOFF : 0);
        int swm = (m & 7) << 3;
        float xb[32];
#pragma unroll
        for (int ssi = 0; ssi < 8; ++ssi) {
            int b0 = (grp * 4 + 64 * ssi) * NN;
            xb[ssi * 4 + 0] = src[b0]; xb[ssi * 4 + 1] = src[b0 + NN];
            xb[ssi * 4 + 2] = src[b0 + 2 * NN]; xb[ssi * 4 + 3] = src[b0 + 3 * NN];
        }
#pragma unroll
        for (int ssi = 0; ssi < 8; ++ssi) {
            int cb = grp * 4 + 64 * ssi;
            uint2 y = { pkbf(xb[ssi * 4 + 0] * sk, xb[ssi * 4 + 1] * sk),
                        pkbf(xb[ssi * 4 + 2] * sk, xb[ssi * 4 + 3] * sk) };
            *(uint2*)&KT[m * 512 + (cb ^ swm)] = y;
            ush* vb = &V[cb * FVSTR + m];
            vb[0] = sbf(xb[ssi * 4 + 0]); vb[FVSTR] = sbf(xb[ssi * 4 + 1]);
            vb[2 * FVSTR] = sbf(xb[ssi * 4 + 2]); vb[3 * FVSTR] = sbf(xb[ssi * 4 + 3]);
        }
    };
    f32x4 acc[8][2];
#pragma unroll
    for (int ci = 0; ci < 8; ++ci) { acc[ci][0] = (f32x4){0,0,0,0}; acc[ci][1] = (f32x4){0,0,0,0}; }
    float den_part = 0.f;
    stage(0, 0);
    const int mt = w >> 2, nt = w & 3, np = w & 1, cg = w >> 1;
    const int g = l >> 4, li = l & 15;
    const int mA = 16 * mt + li, swA = (mA & 7) << 3, nP = 16 * nt + li;
    for (int it = 0; it < 98; ++it) {
        int bb2 = it & 1;
        __syncthreads();
        f32x4 sacc = (f32x4){0,0,0,0};
        const ush* KT = smem + (bb2 ? FKTOFF : 0);
#pragma unroll
        for (int ks = 0; ks < 16; ++ks) {
            short8 af = *(const short8*)&KT[mA * 512 + ((ks * 32 + (g << 3)) ^ swA)];
            sacc = __builtin_amdgcn_mfma_f32_16x16x32_bf16(af, qf[ks], sacc, 0, 0, 0);
        }
        float p0 = __expf(sacc[0]), p1 = __expf(sacc[1]);
        float p2 = __expf(sacc[2]), p3 = __expf(sacc[3]);
        den_part += (p0 + p1) + (p2 + p3);
        uint2 pw = { pkbf(p0, p1), pkbf(p2, p3) };
        *(uint2*)&pp[nP * FVSTR + 16 * mt + 4 * g] = pw;
        if (it != 97) stage(it + 1, bb2 ^ 1);
        __syncthreads();
        const ush* V = smem + FVBASE + (bb2 ? FVOFF : 0);
        short8 bf0 = *(const short8*)&pp[(32 * np + li) * FVSTR + (g << 3)];
        short8 bf1 = *(const short8*)&pp[(32 * np + 16 + li) * FVSTR + (g << 3)];
        const ush* vbase = &V[(128 * cg + li) * FVSTR + (g << 3)];
#pragma unroll
        for (int ci = 0; ci < 8; ++ci) {
            short8 af = *(const short8*)&vbase[ci * 16 * FVSTR];
            acc[ci][0] = __builtin_amdgcn_mfma_f32_16x16x32_bf16(af, bf0, acc[ci][0], 0, 0, 0);
            acc[ci][1] = __builtin_amdgcn_mfma_f32_16x16x32_bf16(af, bf1, acc[ci][1], 0, 0, 0);
        }
    }
    den_part += __shfl_xor(den_part, 16);
    den_part += __shfl_xor(den_part, 32);
    if (l < 16) denbuf[w][l] = den_part;
    __syncthreads();
    float sc0 = 0.001f / (denbuf[2 * np + 0][li] + denbuf[4 + 2 * np + 0][li]);
    float sc1 = 0.001f / (denbuf[2 * np + 1][li] + denbuf[4 + 2 * np + 1][li]);
    float* op = out + (size_t)batch * CC * NN + n0;
    const int nc0 = 16 * (2 * np + 0) + li, nc1 = 16 * (2 * np + 1) + li;
#pragma unroll
    for (int ci = 0; ci < 8; ++ci) {
        int cbase = 16 * (8 * cg + ci) + 4 * g;
#pragma unroll
        for (int r = 0; r < 4; ++r) {
            atomicAdd(&op[(size_t)(cbase + r) * NN + nc0], acc[ci][0][r] * sc0);
            atomicAdd(&op[(size_t)(cbase + r) * NN + nc1], acc[ci][1][r] * sc1);
        }
    }
}

extern "C" void kernel_launch(void* const* d_in, const int* in_sizes, int n_in,
                              void* d_out, int out_size, void* d_ws, size_t ws_size,
                              hipStream_t stream) {
    (void)in_sizes; (void)n_in; (void)out_size;
    const float* f1 = (const float*)d_in[0];
    const float* f2 = (const float*)d_in[1];
    const float* f3 = (const float*)d_in[2];
    float* out = (float*)d_out;
    char* ws = (char*)d_ws;

    if (ws_size >= P_OFS + PER_TILE) {
        size_t tmax = (ws_size - P_OFS) / PER_TILE;
        int T = tmax < 25 ? (int)tmax : 25;
        int rowcap = T * 128;
        size_t PBRel = (size_t)BBATCH * rowcap * VROW;   // bytes per branch
        float* ssq = (float*)(ws + INV_OFS);
        float* den = (float*)(ws + DEN_OFS);
        uch* prep = (uch*)(ws + PREP_OFS);
        uch* vbf = (uch*)(ws + VBF_OFS);
        uch* P = (uch*)(ws + P_OFS);
        hipMemsetAsync(ws, 0, DEN_OFS + 200704, stream);
        prepT_k<<<dim3(49, 8, 24), 256, 0, stream>>>(f1, f2, f3, ssq, prep, vbf);
        rsqrt_k<<<294, 256, 0, stream>>>(ssq);
        for (int cbt = 0; cbt < 25; ) {
            int t = (25 - cbt) < T ? (25 - cbt) : T;
            gemmA_k<<<dim3(25 * t, 8, 2), 256, 0, stream>>>(prep, ssq, P, PBRel, den, cbt, rowcap);
            gemmB_k<<<dim3(4 * t, 8), 256, 0, stream>>>(vbf, P, PBRel, den, f1, out, cbt, rowcap);
            cbt += t;
        }
    } else {
        float* inv = (float*)(ws + INV_OFS);
        norms_k<<<294, 256, 0, stream>>>(f1, f2, f3, inv);
        init_k<<<12544, 256, 0, stream>>>((const float4*)f1, (float4*)out);
        attn_fb_k<<<784, 512, 0, stream>>>(f1, f2, f3, inv, out);
    }
}

// Round 23
// 382.866 us; speedup vs baseline: 1.4337x; 1.0122x over previous
//
// v23 — v22 + ONE change: bijective XCD swizzle (T1/m204) on gemmA's blockIdx.x
#include <hip/hip_runtime.h>
#include <hip/hip_bf16.h>

#define NN 3136
#define CC 512
#define BBATCH 8

typedef unsigned short ush;
typedef unsigned char uch;
typedef __attribute__((ext_vector_type(4))) float f32x4;
typedef __attribute__((ext_vector_type(8))) short short8;

static __device__ __forceinline__ unsigned int pkbf(float a, float b) {
    union { __hip_bfloat162 h; unsigned int u; } v;
    v.h = __float22bfloat162_rn(make_float2(a, b));
    return v.u;
}
static __device__ __forceinline__ ush sbf(float a) {
    union { __hip_bfloat16 h; ush u; } v;
    v.h = __float2bfloat16(a);
    return v.u;
}
static __device__ __forceinline__ unsigned int pk4fp8(float a, float b, float c, float d) {
    unsigned int r = 0;
    r = __builtin_amdgcn_cvt_pk_fp8_f32(a, b, r, false);
    r = __builtin_amdgcn_cvt_pk_fp8_f32(c, d, r, true);
    return r;
}
static __device__ __forceinline__ void gl_lds16(const void* g, void* l) {
    __builtin_amdgcn_global_load_lds((const __attribute__((address_space(1))) void*)g,
                                     (__attribute__((address_space(3))) void*)l, 16, 0, 0);
}

// ---- ws layout (bytes) ----
static constexpr size_t TEN_ELE  = (size_t)BBATCH * NN * CC;   // fp8 bytes
static constexpr size_t VROW     = 3200;
static constexpr size_t VTEN     = (size_t)BBATCH * CC * VROW;
static constexpr size_t INV_OFS  = 0;
static constexpr size_t DEN_OFS  = 301056;
static constexpr size_t PREP_OFS = 501760;
static constexpr size_t VBF_OFS  = PREP_OFS + 3 * TEN_ELE;
static constexpr size_t P_OFS    = VBF_OFS + 2 * VTEN;
static constexpr size_t PER_TILE = 2ull * BBATCH * 128 * VROW;

// ---------------- prepT (unchanged) ----------------
__global__ void prepT_k(const float* __restrict__ f1, const float* __restrict__ f2,
                        const float* __restrict__ f3, float* __restrict__ ssq,
                        uch* __restrict__ prep, uch* __restrict__ vbf) {
    __shared__ float lt[64][65];
    const int tid = threadIdx.x;
    const int xt = blockIdx.x, yc = blockIdx.y, z = blockIdx.z;
    const int t = z >> 3, b = z & 7;
    const float* f = (t == 0) ? f1 : (t == 1) ? f2 : f3;
    const int n0 = xt * 64, c0 = yc * 64;
    const float* src = f + (size_t)b * CC * NN + (size_t)c0 * NN + n0;
    {
        const int col4 = (tid & 15) * 4, rw = tid >> 4;
#pragma unroll
        for (int p = 0; p < 4; ++p) {
            int row = p * 16 + rw;
            f32x4 v = *(const f32x4*)&src[(size_t)row * NN + col4];
            lt[row][col4 + 0] = v[0]; lt[row][col4 + 1] = v[1];
            lt[row][col4 + 2] = v[2]; lt[row][col4 + 3] = v[3];
        }
    }
    __syncthreads();
    {
        uch* dst = prep + (size_t)t * TEN_ELE + ((size_t)b * NN + n0) * CC + c0;
        float* sq = ssq + (size_t)t * BBATCH * NN + (size_t)b * NN + n0;
        const int cchunk = tid & 7, nr = tid >> 3;
#pragma unroll
        for (int p = 0; p < 2; ++p) {
            int n = p * 32 + nr;
            float x0 = lt[cchunk * 8 + 0][n], x1 = lt[cchunk * 8 + 1][n];
            float x2 = lt[cchunk * 8 + 2][n], x3 = lt[cchunk * 8 + 3][n];
            float x4 = lt[cchunk * 8 + 4][n], x5 = lt[cchunk * 8 + 5][n];
            float x6 = lt[cchunk * 8 + 6][n], x7 = lt[cchunk * 8 + 7][n];
            uint2 y = { pk4fp8(x0, x1, x2, x3), pk4fp8(x4, x5, x6, x7) };
            *(uint2*)&dst[(size_t)n * CC + cchunk * 8] = y;
            float s = x0*x0 + x1*x1 + x2*x2 + x3*x3 + x4*x4 + x5*x5 + x6*x6 + x7*x7;
            s += __shfl_xor(s, 1); s += __shfl_xor(s, 2); s += __shfl_xor(s, 4);
            if (cchunk == 0) atomicAdd(&sq[n], s);
        }
    }
    if (t > 0) {
        uch* vout = vbf + (size_t)(t - 1) * VTEN + ((size_t)b * CC + c0) * VROW;
        const int cr = tid >> 2, nq = (tid & 3) * 16;
        float* row = lt[cr];
        uint4 y = { pk4fp8(row[nq+0], row[nq+1], row[nq+2], row[nq+3]),
                    pk4fp8(row[nq+4], row[nq+5], row[nq+6], row[nq+7]),
                    pk4fp8(row[nq+8], row[nq+9], row[nq+10], row[nq+11]),
                    pk4fp8(row[nq+12], row[nq+13], row[nq+14], row[nq+15]) };
        *(uint4*)&vout[(size_t)cr * VROW + n0 + nq] = y;
        if (xt == 48) {
            uint4 z4 = {0u, 0u, 0u, 0u};
            *(uint4*)&vout[(size_t)cr * VROW + 3136 + (tid & 3) * 16] = z4;
        }
    }
}

// ---------------- ssq -> inv ----------------
__global__ void rsqrt_k(float* __restrict__ v) {
    int g = blockIdx.x * 256 + threadIdx.x;
    if (g < 3 * BBATCH * NN) v[g] = 1.0f / fmaxf(sqrtf(v[g]), 1e-12f);
}

// ---------------- gemmA: BK=64 dbuf, XCD-swizzled grid; epilogue exp; P(nt) + den ----------------
__global__ __launch_bounds__(256) void gemmA_k(const uch* __restrict__ prep,
        const float* __restrict__ inv, uch* __restrict__ P, size_t PBRel,
        float* __restrict__ den, int cbt, int rowcap) {
    __shared__ __align__(16) uch sm[34816];       // dbuf 2x16KB; PT bf16 128x136 aliases all
    ush* PT = (ush*)sm;
    const int tid = threadIdx.x, w = tid >> 6, l = tid & 63;
    // T1 bijective XCD swizzle (m204): hardware round-robins blockIdx.x across 8 XCDs;
    // remap so each XCD owns a CONTIGUOUS swz range -> qT/kT panels stay L2-resident.
    const int nx = gridDim.x;
    const int qx = nx >> 3, rx = nx & 7;
    const int xcd = blockIdx.x & 7, lin = blockIdx.x >> 3;
    const int swz = (xcd < rx) ? (xcd * (qx + 1) + lin)
                               : (rx * (qx + 1) + (xcd - rx) * qx + lin);
    const int mt = swz % 25, ntl = swz / 25;
    const int b = blockIdx.y, br = blockIdx.z;
    const int n0 = (cbt + ntl) * 128, m0 = mt * 128;
    const uch* qT = prep + (size_t)b * NN * CC;
    const uch* kT = prep + (size_t)(1 + br) * TEN_ELE + (size_t)b * NN * CC;
    const int srow = l >> 2, c4p = l & 3;         // staging: 16 rows/wave, 4x16B chunks/row
    const int g = l >> 4, li = l & 15, nh = w & 1, mh = w >> 1;
    f32x4 acc[4][4];
#pragma unroll
    for (int i = 0; i < 4; ++i)
#pragma unroll
        for (int j = 0; j < 4; ++j) acc[i][j] = (f32x4){0.f, 0.f, 0.f, 0.f};

    auto stageA = [&](int kk, int bb) {
        int c0k = kk * 64;
        uch* dst = sm + bb * 16384;
#pragma unroll
        for (int i = 0; i < 2; ++i) {
            int rowT = i * 64 + w * 16 + srow;    // 0..127
            int rA = n0 + rowT; rA = rA < NN ? rA : NN - 1;
            int rB = m0 + rowT; rB = rB < NN ? rB : NN - 1;
            int co = (c4p ^ ((rowT >> 1) & 3)) << 4;
            gl_lds16(qT + (size_t)rA * CC + c0k + co, dst + i * 4096 + w * 1024);
            gl_lds16(kT + (size_t)rB * CC + c0k + co, dst + 8192 + i * 4096 + w * 1024);
        }
    };

    stageA(0, 0);
    __syncthreads();                               // buf0 ready

    for (int kk = 0; kk < 8; ++kk) {
        int cur = kk & 1;
        if (kk < 7) stageA(kk + 1, cur ^ 1);       // prefetch next phase into other buffer
        const uch* smc = sm + cur * 16384;
#pragma unroll
        for (int ks = 0; ks < 2; ++ks) {
            long af[4], bf[4];
            int kc = ks * 2 + (g >> 1);
#pragma unroll
            for (int i = 0; i < 4; ++i) {
                int rA = nh * 64 + i * 16 + li;
                af[i] = *(const long*)(smc + rA * 64 +
                        (((kc ^ ((rA >> 1) & 3)) << 4) | ((g & 1) << 3)));
                int rB = mh * 64 + i * 16 + li;
                bf[i] = *(const long*)(smc + 8192 + rB * 64 +
                        (((kc ^ ((rB >> 1) & 3)) << 4) | ((g & 1) << 3)));
            }
#pragma unroll
            for (int i = 0; i < 4; ++i)
#pragma unroll
                for (int j = 0; j < 4; ++j)
                    acc[i][j] = __builtin_amdgcn_mfma_f32_16x16x32_fp8_fp8(af[i], bf[j], acc[i][j], 0, 0, 0);
        }
        __syncthreads();                           // reads done + staged loads drained
    }
    // epilogue: s = acc * (-inv1[n]) * invk[m]; exp; PT bounce; fp8 stores (nt) + den
    const float* i1p = inv + (size_t)b * NN;
    const float* ikp = inv + (size_t)(1 + br) * (BBATCH * NN) + (size_t)b * NN;
    float ikv[4], i1v[4][4];
#pragma unroll
    for (int j = 0; j < 4; ++j) {
        int m = m0 + mh * 64 + j * 16 + li;
        ikv[j] = ikp[m < NN ? m : NN - 1];
    }
#pragma unroll
    for (int i = 0; i < 4; ++i)
#pragma unroll
        for (int r = 0; r < 4; ++r) {
            int n = n0 + nh * 64 + i * 16 + 4 * g + r;
            i1v[i][r] = -i1p[n < NN ? n : NN - 1];
        }
#pragma unroll
    for (int i = 0; i < 4; ++i)
#pragma unroll
        for (int j = 0; j < 4; ++j) {
            int col = mh * 64 + j * 16 + li;
#pragma unroll
            for (int r = 0; r < 4; ++r) {
                int row = nh * 64 + i * 16 + 4 * g + r;
                PT[row * 136 + col] = sbf(__expf(acc[i][j][r] * i1v[i][r] * ikv[j]));
            }
        }
    __syncthreads();
    const int rowlim = (NN - n0) < 128 ? (NN - n0) : 128;
    const int mchunks = (NN - m0) < 128 ? ((NN - m0) >> 3) : 16;
    uch* Pg = P + (size_t)br * PBRel + ((size_t)b * rowcap + (size_t)ntl * 128) * VROW;
    float* denp = den + (size_t)(br * BBATCH + b) * NN;
    const int ck = tid & 15, rbase = tid >> 4;
#pragma unroll
    for (int pass = 0; pass < 8; ++pass) {
        int rr = rbase + pass * 16;
        uint4 v = *(const uint4*)&PT[rr * 136 + ck * 8];
        unsigned vv[4] = { v.x, v.y, v.z, v.w };
        float fv[8];
#pragma unroll
        for (int q = 0; q < 4; ++q) {
            union { unsigned u; float f; } lo, hi;
            lo.u = vv[q] << 16; hi.u = vv[q] & 0xffff0000u;
            fv[2 * q] = lo.f; fv[2 * q + 1] = hi.f;
        }
        float s = 0.f;
        if (ck < mchunks)
            s = ((fv[0] + fv[1]) + (fv[2] + fv[3])) + ((fv[4] + fv[5]) + (fv[6] + fv[7]));
        s += __shfl_xor(s, 1); s += __shfl_xor(s, 2);
        s += __shfl_xor(s, 4); s += __shfl_xor(s, 8);
        if (ck == 0 && rr < rowlim) atomicAdd(&denp[n0 + rr], s);
        if (rr < rowlim) {
            uint2 pv = {0u, 0u};
            if (ck < mchunks) {
                pv.x = pk4fp8(fv[0], fv[1], fv[2], fv[3]);
                pv.y = pk4fp8(fv[4], fv[5], fv[6], fv[7]);
            }
            unsigned long long pu = ((unsigned long long)pv.y << 32) | (unsigned long long)pv.x;
            __builtin_nontemporal_store(pu,
                (unsigned long long*)&Pg[(size_t)rr * VROW + m0 + ck * 8]);
        }
    }
}

// ---------------- gemmB: 128² tile + 2-phase dbuf pipeline (proven v17, untouched) ----------------
__global__ __launch_bounds__(256) void gemmB_k(const uch* __restrict__ vbf,
        const uch* __restrict__ P, size_t PBRel, const float* __restrict__ den,
        const float* __restrict__ fm1, float* __restrict__ out, int cbt, int rowcap) {
    __shared__ __align__(16) uch sm[65536];       // 2 x { V 16KB | P 16KB }
    const int tid = threadIdx.x, w = tid >> 6, l = tid & 63;
    const int ct = blockIdx.x & 3, ntl = blockIdx.x >> 2;
    const int b = blockIdx.y;
    const int c0 = ct * 128, n0 = (cbt + ntl) * 128;
    const int lr8 = l >> 3, c4p = l & 7;
    const int g = l >> 4, li = l & 15, ch = w & 1, nh = w >> 1;
    const float* d2p = den + (size_t)b * NN;
    const float* d3p = den + (size_t)(BBATCH + b) * NN;
    float d2[4], d3[4];
#pragma unroll
    for (int j = 0; j < 4; ++j) {
        int n = n0 + nh * 64 + j * 16 + li;
        int nc = n < NN ? n : NN - 1;
        d2[j] = d2p[nc]; d3[j] = d3p[nc];
    }
    f32x4 acc[4][4];
#pragma unroll
    for (int i = 0; i < 4; ++i)
#pragma unroll
        for (int j = 0; j < 4; ++j) acc[i][j] = (f32x4){0.f, 0.f, 0.f, 0.f};
    const int rowclamp = (NN - 1 - n0) < 127 ? (NN - 1 - n0) : 127;

    auto stage = [&](int gk, int bb) {
        int brr = gk < 25 ? 1 : 0;                 // P3 first, ratio-fold, then P2
        int km = gk < 25 ? gk : gk - 25;
        const uch* vA = vbf + (size_t)brr * VTEN + (size_t)b * CC * VROW;
        const uch* pB = P + (size_t)brr * PBRel + ((size_t)b * rowcap + (size_t)ntl * 128) * VROW;
        int mm0 = km * 128;
        uch* dst = sm + bb * 32768;
#pragma unroll
        for (int i = 0; i < 4; ++i) {
            int rowT = i * 32 + w * 8 + lr8;
            int co = (c4p ^ (rowT & 7)) << 4;
            int rloc = rowT < rowclamp ? rowT : rowclamp;
            gl_lds16(vA + (size_t)(c0 + rowT) * VROW + mm0 + co, dst + i * 4096 + w * 1024);
            gl_lds16(pB + (size_t)rloc * VROW + mm0 + co, dst + 16384 + i * 4096 + w * 1024);
        }
    };

    stage(0, 0);
    __syncthreads();

    for (int gk = 0; gk < 50; ++gk) {
        int cur = gk & 1;
        if (gk < 49) stage(gk + 1, cur ^ 1);
        const uch* smc = sm + cur * 32768;
#pragma unroll
        for (int ks = 0; ks < 4; ++ks) {
            long af[4], bf[4];
#pragma unroll
            for (int i = 0; i < 4; ++i) {
                int rA = ch * 64 + i * 16 + li;
                af[i] = *(const long*)(smc + rA * 128 +
                        ((((2 * ks + (g >> 1)) ^ (rA & 7)) << 4) | ((g & 1) << 3)));
                int rB = nh * 64 + i * 16 + li;
                bf[i] = *(const long*)(smc + 16384 + rB * 128 +
                        ((((2 * ks + (g >> 1)) ^ (rB & 7)) << 4) | ((g & 1) << 3)));
            }
#pragma unroll
            for (int i = 0; i < 4; ++i)
#pragma unroll
                for (int j = 0; j < 4; ++j)
                    acc[i][j] = __builtin_amdgcn_mfma_f32_16x16x32_fp8_fp8(af[i], bf[j], acc[i][j], 0, 0, 0);
        }
        if (gk == 24) {
#pragma unroll
            for (int j = 0; j < 4; ++j) {
                float ratio = d2[j] / fmaxf(d3[j], 1e-30f);
#pragma unroll
                for (int i = 0; i < 4; ++i)
#pragma unroll
                    for (int r = 0; r < 4; ++r) acc[i][j][r] *= ratio;
            }
        }
        __syncthreads();
    }
    const float* fb = fm1 + (size_t)b * CC * NN;
    float* ob = out + (size_t)b * CC * NN;
#pragma unroll
    for (int j = 0; j < 4; ++j) {
        int n = n0 + nh * 64 + j * 16 + li;
        if (n < NN) {
            float s2 = 0.001f / fmaxf(d2[j], 1e-30f);
#pragma unroll
            for (int i = 0; i < 4; ++i) {
                int cc = c0 + ch * 64 + i * 16 + 4 * g;
#pragma unroll
                for (int r = 0; r < 4; ++r) {
                    size_t o = (size_t)(cc + r) * NN + n;
                    ob[o] = fb[o] + s2 * acc[i][j][r];
                }
            }
        }
    }
}

// ================= fallback (proven R5 fused kernel, used only if ws too small) ===============
__global__ void norms_k(const float* __restrict__ f1, const float* __restrict__ f2,
                        const float* __restrict__ f3, float* __restrict__ inv) {
    int gg = blockIdx.x * 256 + threadIdx.x;
    int t = gg / (BBATCH * NN);
    int r = gg - t * (BBATCH * NN);
    int b = r / NN;
    int n = r - b * NN;
    const float* f = (t == 0) ? f1 : (t == 1) ? f2 : f3;
    const float* p = f + (size_t)b * CC * NN + n;
    float ss = 0.f;
#pragma unroll 8
    for (int c = 0; c < CC; ++c) { float x = p[(size_t)c * NN]; ss = fmaf(x, x, ss); }
    inv[gg] = 1.0f / fmaxf(sqrtf(ss), 1e-12f);
}
__global__ void init_k(const float4* __restrict__ src, float4* __restrict__ dst) {
    int gg = blockIdx.x * 256 + threadIdx.x;
    dst[gg] = src[gg];
}
static constexpr int FKTOFF = 16384, FVBASE = 32768, FVOFF = 20480, FPBASE = 73728, FVSTR = 40;
__launch_bounds__(512, 2)
__global__ void attn_fb_k(const float* __restrict__ fq_all, const float* __restrict__ f2_all,
                          const float* __restrict__ f3_all, const float* __restrict__ invws,
                          float* __restrict__ out) {
    __shared__ __align__(16) ush smem[2 * 16384 + 2 * 20480 + 64 * 40];
    __shared__ float denbuf[8][16];
    ush* pp = smem + FPBASE;
    ush* qstage = smem;
    const int tid = threadIdx.x, w = tid >> 6, l = tid & 63;
    const int u = blockIdx.x, batch = u & 7, unit = u >> 3, br = unit & 1, qt = unit >> 1;
    const int n0 = qt * 64;
    const float* fq = fq_all + (size_t)batch * CC * NN;
    const float* fk = (br ? f3_all : f2_all) + (size_t)batch * CC * NN;
    const float* inv1 = invws + batch * NN;
    const float* invk = invws + (1 + br) * (BBATCH * NN) + batch * NN;
    {
        int n = tid & 63, grp = tid >> 6;
        float s = -inv1[n0 + n];
        const float* src = fq + n0 + n;
        int sw = (n & 7) << 3;
#pragma unroll 4
        for (int ssi = 0; ssi < 16; ++ssi) {
            int cb = grp * 4 + 32 * ssi; int b0 = cb * NN;
            uint2 y = { pkbf(src[b0] * s, src[b0 + NN] * s),
                        pkbf(src[b0 + 2 * NN] * s, src[b0 + 3 * NN] * s) };
            *(uint2*)&qstage[n * 512 + (cb ^ sw)] = y;
        }
    }
    __syncthreads();
    short8 qf[16];
    {
        int nQ = 16 * (w & 3) + (l & 15);
        int sw = (nQ & 7) << 3;
#pragma unroll
        for (int ks = 0; ks < 16; ++ks)
            qf[ks] = *(const short8*)&qstage[nQ * 512 + ((ks * 32 + ((l >> 4) << 3)) ^ sw)];
    }
    __syncthreads();
    auto stage = [&](int it, int bb2) {
        int m = tid & 31, grp = tid >> 5;
        int m0 = it * 32;
        float sk = invk[m0 + m];
        const float* src = fk + m0 + m;
        ush* KT = smem + (bb2 ? FKTOFF : 0);
        ush* V = smem + FVBASE + (bb2 ? FVOFF : 0);
        int swm = (m & 7) << 3;
        float xb[32];
#pragma unroll
        for (int ssi = 0; ssi < 8; ++ssi) {
            int b0 = (grp * 4 + 64 * ssi) * NN;
            xb[ssi * 4 + 0] = src[b0]; xb[ssi * 4 + 1] = src[b0 + NN];
            xb[ssi * 4 + 2] = src[b0 + 2 * NN]; xb[ssi * 4 + 3] = src[b0 + 3 * NN];
        }
#pragma unroll
        for (int ssi = 0; ssi < 8; ++ssi) {
            int cb = grp * 4 + 64 * ssi;
            uint2 y = { pkbf(xb[ssi * 4 + 0] * sk, xb[ssi * 4 + 1] * sk),
                        pkbf(xb[ssi * 4 + 2] * sk, xb[ssi * 4 + 3] * sk) };
            *(uint2*)&KT[m * 512 + (cb ^ swm)] = y;
            ush* vb = &V[cb * FVSTR + m];
            vb[0] = sbf(xb[ssi * 4 + 0]); vb[FVSTR] = sbf(xb[ssi * 4 + 1]);
            vb[2 * FVSTR] = sbf(xb[ssi * 4 + 2]); vb[3 * FVSTR] = sbf(xb[ssi * 4 + 3]);
        }
    };
    f32x4 acc[8][2];
#pragma unroll
    for (int ci = 0; ci < 8; ++ci) { acc[ci][0] = (f32x4){0,0,0,0}; acc[ci][1] = (f32x4){0,0,0,0}; }
    float den_part = 0.f;
    stage(0, 0);
    const int mt = w >> 2, nt = w & 3, np = w & 1, cg = w >> 1;
    const int g = l >> 4, li = l & 15;
    const int mA = 16 * mt + li, swA = (mA & 7) << 3, nP = 16 * nt + li;
    for (int it = 0; it < 98; ++it) {
        int bb2 = it & 1;
        __syncthreads();
        f32x4 sacc = (f32x4){0,0,0,0};
        const ush* KT = smem + (bb2 ? FKTOFF : 0);
#pragma unroll
        for (int ks = 0; ks < 16; ++ks) {
            short8 af = *(const short8*)&KT[mA * 512 + ((ks * 32 + (g << 3)) ^ swA)];
            sacc = __builtin_amdgcn_mfma_f32_16x16x32_bf16(af, qf[ks], sacc, 0, 0, 0);
        }
        float p0 = __expf(sacc[0]), p1 = __expf(sacc[1]);
        float p2 = __expf(sacc[2]), p3 = __expf(sacc[3]);
        den_part += (p0 + p1) + (p2 + p3);
        uint2 pw = { pkbf(p0, p1), pkbf(p2, p3) };
        *(uint2*)&pp[nP * FVSTR + 16 * mt + 4 * g] = pw;
        if (it != 97) stage(it + 1, bb2 ^ 1);
        __syncthreads();
        const ush* V = smem + FVBASE + (bb2 ? FVOFF : 0);
        short8 bf0 = *(const short8*)&pp[(32 * np + li) * FVSTR + (g << 3)];
        short8 bf1 = *(const short8*)&pp[(32 * np + 16 + li) * FVSTR + (g << 3)];
        const ush* vbase = &V[(128 * cg + li) * FVSTR + (g << 3)];
#pragma unroll
        for (int ci = 0; ci < 8; ++ci) {
            short8 af = *(const short8*)&vbase[ci * 16 * FVSTR];
            acc[ci][0] = __builtin_amdgcn_mfma_f32_16x16x32_bf16(af, bf0, acc[ci][0], 0, 0, 0);
            acc[ci][1] = __builtin_amdgcn_mfma_f32_16x16x32_bf16(af, bf1, acc[ci][1], 0, 0, 0);
        }
    }
    den_part += __shfl_xor(den_part, 16);
    den_part += __shfl_xor(den_part, 32);
    if (l < 16) denbuf[w][l] = den_part;
    __syncthreads();
    float sc0 = 0.001f / (denbuf[2 * np + 0][li] + denbuf[4 + 2 * np + 0][li]);
    float sc1 = 0.001f / (denbuf[2 * np + 1][li] + denbuf[4 + 2 * np + 1][li]);
    float* op = out + (size_t)batch * CC * NN + n0;
    const int nc0 = 16 * (2 * np + 0) + li, nc1 = 16 * (2 * np + 1) + li;
#pragma unroll
    for (int ci = 0; ci < 8; ++ci) {
        int cbase = 16 * (8 * cg + ci) + 4 * g;
#pragma unroll
        for (int r = 0; r < 4; ++r) {
            atomicAdd(&op[(size_t)(cbase + r) * NN + nc0], acc[ci][0][r] * sc0);
            atomicAdd(&op[(size_t)(cbase + r) * NN + nc1], acc[ci][1][r] * sc1);
        }
    }
}

extern "C" void kernel_launch(void* const* d_in, const int* in_sizes, int n_in,
                              void* d_out, int out_size, void* d_ws, size_t ws_size,
                              hipStream_t stream) {
    (void)in_sizes; (void)n_in; (void)out_size;
    const float* f1 = (const float*)d_in[0];
    const float* f2 = (const float*)d_in[1];
    const float* f3 = (const float*)d_in[2];
    float* out = (float*)d_out;
    char* ws = (char*)d_ws;

    if (ws_size >= P_OFS + PER_TILE) {
        size_t tmax = (ws_size - P_OFS) / PER_TILE;
        int T = tmax < 25 ? (int)tmax : 25;
        int rowcap = T * 128;
        size_t PBRel = (size_t)BBATCH * rowcap * VROW;   // bytes per branch
        float* ssq = (float*)(ws + INV_OFS);
        float* den = (float*)(ws + DEN_OFS);
        uch* prep = (uch*)(ws + PREP_OFS);
        uch* vbf = (uch*)(ws + VBF_OFS);
        uch* P = (uch*)(ws + P_OFS);
        hipMemsetAsync(ws, 0, DEN_OFS + 200704, stream);
        prepT_k<<<dim3(49, 8, 24), 256, 0, stream>>>(f1, f2, f3, ssq, prep, vbf);
        rsqrt_k<<<294, 256, 0, stream>>>(ssq);
        for (int cbt = 0; cbt < 25; ) {
            int t = (25 - cbt) < T ? (25 - cbt) : T;
            gemmA_k<<<dim3(25 * t, 8, 2), 256, 0, stream>>>(prep, ssq, P, PBRel, den, cbt, rowcap);
            gemmB_k<<<dim3(4 * t, 8), 256, 0, stream>>>(vbf, P, PBRel, den, f1, out, cbt, rowcap);
            cbt += t;
        }
    } else {
        float* inv = (float*)(ws + INV_OFS);
        norms_k<<<294, 256, 0, stream>>>(f1, f2, f3, inv);
        init_k<<<12544, 256, 0, stream>>>((const float4*)f1, (float4*)out);
        attn_fb_k<<<784, 512, 0, stream>>>(f1, f2, f3, inv, out);
    }
}